// Round 3
// baseline (6598.339 us; speedup 1.0000x reference)
//
#include <hip/hip_runtime.h>
#include <math.h>

#define N_NODES 50000
#define HIDD 128
#define HEADS 8
#define HDIM 16
#define NE 800000

// ---------- ordered-uint encoding for float atomicMax ----------
__device__ __forceinline__ unsigned enc_f(float f) {
  unsigned u = __float_as_uint(f);
  return (u & 0x80000000u) ? ~u : (u | 0x80000000u);
}
__device__ __forceinline__ float dec_f(unsigned u) {
  return __uint_as_float((u & 0x80000000u) ? (u ^ 0x80000000u) : ~u);
}

// ---------- dtype-robust edge-index load (clamped: can never fault) ----------
__device__ __forceinline__ int load_idx(const void* ei, int is64, long long pos) {
  long long v = is64 ? ((const long long*)ei)[pos]
                     : (long long)((const int*)ei)[pos];
  unsigned uv = (unsigned)v;
  return (uv < N_NODES) ? (int)uv : 0;
}

// int64 vs int32 detect: LE int64 < 2^31 has every odd int32 word == 0.
__global__ void detect_kernel(const unsigned* __restrict__ ei_raw, int* flag) {
  __shared__ int any_nonzero;
  if (threadIdx.x == 0) any_nonzero = 0;
  __syncthreads();
  if (threadIdx.x < 128) {
    if (ei_raw[2 * threadIdx.x + 1] != 0u) atomicOr(&any_nonzero, 1);
  }
  __syncthreads();
  if (threadIdx.x == 0) *flag = any_nonzero ? 0 : 1;  // 1 => int64
}

// ---------- ws-too-small probe: absmax ~= ws_size in MB ----------
__global__ __launch_bounds__(256) void probe_kernel(float* out, int n, float mb) {
  int i = blockIdx.x * 256 + threadIdx.x;
  if (i < n) out[i] = (i == 0) ? mb : 0.f;
}

// ---------- epilogue functors ----------
struct EpiNone {
  __device__ __forceinline__ float operator()(float a, int, int) const { return a; }
};
struct EpiBias {
  const float* b;  // pre-offset on host
  __device__ __forceinline__ float operator()(float a, int, int c) const { return a + b[c]; }
};
struct EpiGelu {
  const float* b;
  __device__ __forceinline__ float operator()(float a, int, int c) const {
    float t = a + b[c];
    float u = 0.7978845608028654f * (t + 0.044715f * t * t * t);
    return 0.5f * t * (1.f + tanhf(u));
  }
};
struct EpiResGate {  // xres[r,c] + gate[r,c] * (a + b[c]); gate is [M,128]
  const float* b;
  const float* xres;
  const float* gate;
  __device__ __forceinline__ float operator()(float a, int r, int c) const {
    return xres[(size_t)r * HIDD + c] + gate[(size_t)r * HIDD + c] * (a + b[c]);
  }
};

// ---------- tiled fp32 GEMM: C[M,N](ldc=N) = epi(A[M,K] @ B[K,*](ldb)) ----------
// 64x64 tile, TK=64, 256 threads, 4x4 acc. B pointer pre-offset for col slices.
template <class Epi>
__global__ __launch_bounds__(256) void gemm_kernel(
    const float* __restrict__ A, const float* __restrict__ B, int ldb,
    float* __restrict__ C, int M, int N, int K, Epi epi) {
  __shared__ float As[64][68];
  __shared__ float Bs[64][64];

  const int tid = threadIdx.x;
  const int tx = tid & 15;
  const int ty = tid >> 4;
  const int row0 = blockIdx.x * 64;
  const int col0 = blockIdx.y * 64;

  float acc[4][4] = {};

  for (int k0 = 0; k0 < K; k0 += 64) {
#pragma unroll
    for (int i = 0; i < 4; i++) {
      int idx = tid + i * 256;
      int r = idx >> 4;
      int cc = (idx & 15) << 2;
      int gr = row0 + r;
      float4 v = make_float4(0.f, 0.f, 0.f, 0.f);
      if (gr < M) v = *(const float4*)(A + (size_t)gr * K + k0 + cc);
      *(float4*)&As[r][cc] = v;
    }
#pragma unroll
    for (int i = 0; i < 4; i++) {
      int idx = tid + i * 256;
      int r = idx >> 4;
      int cc = (idx & 15) << 2;
      *(float4*)&Bs[r][cc] = *(const float4*)(B + (size_t)(k0 + r) * ldb + col0 + cc);
    }
    __syncthreads();

#pragma unroll
    for (int kk = 0; kk < 64; kk++) {
      float a0 = As[ty * 4 + 0][kk];
      float a1 = As[ty * 4 + 1][kk];
      float a2 = As[ty * 4 + 2][kk];
      float a3 = As[ty * 4 + 3][kk];
      float4 b = *(float4*)&Bs[kk][tx * 4];
      acc[0][0] += a0 * b.x; acc[0][1] += a0 * b.y; acc[0][2] += a0 * b.z; acc[0][3] += a0 * b.w;
      acc[1][0] += a1 * b.x; acc[1][1] += a1 * b.y; acc[1][2] += a1 * b.z; acc[1][3] += a1 * b.w;
      acc[2][0] += a2 * b.x; acc[2][1] += a2 * b.y; acc[2][2] += a2 * b.z; acc[2][3] += a2 * b.w;
      acc[3][0] += a3 * b.x; acc[3][1] += a3 * b.y; acc[3][2] += a3 * b.z; acc[3][3] += a3 * b.w;
    }
    __syncthreads();
  }

#pragma unroll
  for (int i = 0; i < 4; i++) {
    int gr = row0 + ty * 4 + i;
    if (gr >= M) break;
    int gc = col0 + tx * 4;
    float4 o;
    o.x = epi(acc[i][0], gr, gc + 0);
    o.y = epi(acc[i][1], gr, gc + 1);
    o.z = epi(acc[i][2], gr, gc + 2);
    o.w = epi(acc[i][3], gr, gc + 3);
    *(float4*)(C + (size_t)gr * N + gc) = o;
  }
}

// ---------- silu elementwise: sgate = c * sigmoid(c) ----------
__global__ __launch_bounds__(256) void silu_kernel(const float* __restrict__ c,
                                                   float* __restrict__ sg) {
  int i = blockIdx.x * 256 + threadIdx.x;
  if (i < N_NODES * HIDD) {
    float v = c[i];
    sg[i] = v / (1.f + __expf(-v));
  }
}

// ---------- LN + modulate: shsc rows = [sh(128)|sc(128)], stride 256 ----------
__global__ __launch_bounds__(256) void ln_mod_kernel(
    const float* __restrict__ x, const float* __restrict__ shsc,
    float* __restrict__ out) {
  int wave = threadIdx.x >> 6;
  int lane = threadIdx.x & 63;
  int row = blockIdx.x * 4 + wave;
  if (row >= N_NODES) return;
  float2 v = *(const float2*)(x + (size_t)row * HIDD + lane * 2);
  float s = v.x + v.y;
  float sq = v.x * v.x + v.y * v.y;
#pragma unroll
  for (int o = 32; o >= 1; o >>= 1) {
    s += __shfl_xor(s, o);
    sq += __shfl_xor(sq, o);
  }
  float m = s * (1.f / 128.f);
  float var = sq * (1.f / 128.f) - m * m;
  float rs = rsqrtf(var + 1e-6f);
  float2 sh = *(const float2*)(shsc + (size_t)row * 256 + lane * 2);
  float2 sc = *(const float2*)(shsc + (size_t)row * 256 + 128 + lane * 2);
  float2 o;
  o.x = (v.x - m) * rs * (1.f + sc.x) + sh.x;
  o.y = (v.y - m) * rs * (1.f + sc.y) + sh.y;
  *(float2*)(out + (size_t)row * HIDD + lane * 2) = o;
}

// ---------- zero helpers ----------
__global__ __launch_bounds__(256) void zero_kernel(float* p, int n) {
  int i = blockIdx.x * 256 + threadIdx.x;
  if (i < n) p[i] = 0.f;
}
__global__ __launch_bounds__(256) void init_den_smax(float* den, unsigned* smax) {
  int i = blockIdx.x * 256 + threadIdx.x;
  if (i < N_NODES * HEADS) {
    den[i] = 0.f;
    smax[i] = 0u;  // below enc(any finite); empty segments never read back
  }
}

// ---------- edge pass 1: score + segment max. qk rows = [q(128)|k(128)] ----------
__global__ __launch_bounds__(256) void edge_score_kernel(
    const void* __restrict__ ei, const int* __restrict__ flag,
    const float* __restrict__ qk, float* __restrict__ score,
    unsigned* __restrict__ smax) {
  int idx = blockIdx.x * 256 + threadIdx.x;
  if (idx >= NE * HEADS) return;
  int is64 = *flag;
  int e = idx >> 3, h = idx & 7;
  int src = load_idx(ei, is64, e);
  int dst = load_idx(ei, is64, (long long)NE + e);
  const float4* qp = (const float4*)(qk + (size_t)dst * 256 + h * HDIM);
  const float4* kp = (const float4*)(qk + (size_t)src * 256 + 128 + h * HDIM);
  float s = 0.f;
#pragma unroll
  for (int i = 0; i < 4; i++) {
    float4 a = qp[i], b = kp[i];
    s += a.x * b.x + a.y * b.y + a.z * b.z + a.w * b.w;
  }
  s *= 0.25f;  // 1/sqrt(16)
  score[idx] = s;
  atomicMax(smax + (size_t)dst * HEADS + h, enc_f(s));
}

// ---------- edge pass 2: exp + segment sum ----------
__global__ __launch_bounds__(256) void edge_exp_kernel(
    const void* __restrict__ ei, const int* __restrict__ flag,
    float* __restrict__ score, const unsigned* __restrict__ smax,
    float* __restrict__ den) {
  int idx = blockIdx.x * 256 + threadIdx.x;
  if (idx >= NE * HEADS) return;
  int is64 = *flag;
  int e = idx >> 3, h = idx & 7;
  int dst = load_idx(ei, is64, (long long)NE + e);
  float mx = dec_f(smax[(size_t)dst * HEADS + h]);
  float ex = __expf(score[idx] - mx);
  score[idx] = ex;
  atomicAdd(den + (size_t)dst * HEADS + h, ex);
}

// ---------- edge pass 3: aggregation (v is [N,128]) ----------
__global__ __launch_bounds__(256) void edge_agg_kernel(
    const void* __restrict__ ei, const int* __restrict__ flag,
    const float* __restrict__ v, const float* __restrict__ ex,
    const float* __restrict__ den, float* __restrict__ attn_out) {
  int idx = blockIdx.x * 256 + threadIdx.x;
  if (idx >= NE * HEADS) return;
  int is64 = *flag;
  int e = idx >> 3, h = idx & 7;
  int src = load_idx(ei, is64, e);
  int dst = load_idx(ei, is64, (long long)NE + e);
  float a = ex[idx] / den[(size_t)dst * HEADS + h];
  const float4* vp = (const float4*)(v + (size_t)src * HIDD + h * HDIM);
  float* op = attn_out + (size_t)dst * HIDD + h * HDIM;
#pragma unroll
  for (int i = 0; i < 4; i++) {
    float4 w = vp[i];
    atomicAdd(op + i * 4 + 0, w.x * a);
    atomicAdd(op + i * 4 + 1, w.y * a);
    atomicAdd(op + i * 4 + 2, w.z * a);
    atomicAdd(op + i * 4 + 3, w.w * a);
  }
}

extern "C" void kernel_launch(void* const* d_in, const int* in_sizes, int n_in,
                              void* d_out, int out_size, void* d_ws, size_t ws_size,
                              hipStream_t stream) {
  const float* x      = (const float*)d_in[0];
  const void*  ei     = d_in[1];
  const float* c      = (const float*)d_in[2];
  const float* w_qkv  = (const float*)d_in[3];
  const float* w_proj = (const float*)d_in[4];
  const float* b_proj = (const float*)d_in[5];
  const float* w_mlp1 = (const float*)d_in[6];
  const float* b_mlp1 = (const float*)d_in[7];
  const float* w_mlp2 = (const float*)d_in[8];
  const float* b_mlp2 = (const float*)d_in[9];
  const float* w_ada  = (const float*)d_in[10];
  const float* b_ada  = (const float*)d_in[11];
  float* out = (float*)d_out;

  // ---- pool layout (floats), 157 MB total, heavy overlay ----
  // [xm 6.4M][sgate 6.4M][P1 12.8M][P3 12.8M][den .4M][smax .4M][flag]
  const size_t NM = (size_t)N_NODES;
  float* pool = (float*)d_ws;
  float* xm    = pool;                       // N*128; LN1 out, later LN2 out
  float* sgate = xm + NM * 128;              // N*128; silu(c), lives to end
  float* P1    = sgate + NM * 128;           // N*256; modbuf/score/gbuf/modchunk
  float* P3    = P1 + NM * 256;              // N*256; qk -> v|attn_out
  float* den   = P3 + NM * 256;              // N*8
  unsigned* smax = (unsigned*)(den + NM * 8);  // N*8
  int* eflag   = (int*)(smax + NM * 8);      // 1
  float* h1    = P1;                         // N*512 spans P1+P3 (adjacent)
  float* vbuf  = P3;                         // N*128
  float* attn  = P3 + NM * 128;              // N*128
  float* score = P1;                         // E*8 = 6.4M <= 12.8M

  const size_t req_bytes = ((NM * 128) * 2 + (NM * 256) * 2 + NM * 16 + 16) * 4;
  dim3 blk(256);
  if (ws_size < req_bytes) {
    // workspace too small: emit probe (absmax ~= ws_size in MB) instead of crashing
    probe_kernel<<<dim3((out_size + 255) / 256), blk, 0, stream>>>(
        out, out_size, (float)(ws_size >> 20));
    return;
  }

  const int MB = (N_NODES + 63) / 64;
  const int EB = (NE * HEADS + 255) / 256;
  const int NB128 = (N_NODES * 128 + 255) / 256;

  // 0. dtype detect + den/smax init
  detect_kernel<<<dim3(1), blk, 0, stream>>>((const unsigned*)ei, eflag);
  init_den_smax<<<dim3((N_NODES * 8 + 255) / 256), blk, 0, stream>>>(den, smax);

  // 1. sgate = silu(c)
  silu_kernel<<<dim3(NB128), blk, 0, stream>>>(c, sgate);

  // 2. P1 = sgate @ w_ada[:,0:256] + b_ada[0:256]   (sh_msa|sc_msa)
  gemm_kernel<EpiBias><<<dim3(MB, 4), blk, 0, stream>>>(
      sgate, w_ada, 768, P1, N_NODES, 256, 128, EpiBias{b_ada});

  // 3. xm = modulate(ln(x), sh_msa, sc_msa)
  ln_mod_kernel<<<dim3((N_NODES + 3) / 4), blk, 0, stream>>>(x, P1, xm);

  // 4. P3 = xm @ w_qkv[:,0:256]   (q|k)
  gemm_kernel<EpiNone><<<dim3(MB, 4), blk, 0, stream>>>(
      xm, w_qkv, 384, P3, N_NODES, 256, 128, EpiNone{});

  // 5-6. scores + softmax denominators (score overwrites P1; sh/sc dead)
  edge_score_kernel<<<dim3(EB), blk, 0, stream>>>(ei, eflag, P3, score, smax);
  edge_exp_kernel<<<dim3(EB), blk, 0, stream>>>(ei, eflag, score, smax, den);

  // 7. qk dead: zero attn half of P3, compute v into other half
  zero_kernel<<<dim3(NB128), blk, 0, stream>>>(attn, N_NODES * 128);
  gemm_kernel<EpiNone><<<dim3(MB, 2), blk, 0, stream>>>(
      xm, w_qkv + 256, 384, vbuf, N_NODES, 128, 128, EpiNone{});

  // 8. aggregation
  edge_agg_kernel<<<dim3(EB), blk, 0, stream>>>(ei, eflag, vbuf, score, den, attn);

  // 9. g_msa into P1 (score dead)
  gemm_kernel<EpiBias><<<dim3(MB, 2), blk, 0, stream>>>(
      sgate, w_ada + 256, 768, P1, N_NODES, 128, 128, EpiBias{b_ada + 256});

  // 10. x1(d_out) = x + g_msa * (attn @ w_proj + b_proj)
  gemm_kernel<EpiResGate><<<dim3(MB, 2), blk, 0, stream>>>(
      attn, w_proj, 128, out, N_NODES, 128, 128, EpiResGate{b_proj, x, P1});

  // 11. P1 = sgate @ w_ada[:,384:640] + b   (sh_mlp|sc_mlp)
  gemm_kernel<EpiBias><<<dim3(MB, 4), blk, 0, stream>>>(
      sgate, w_ada + 384, 768, P1, N_NODES, 256, 128, EpiBias{b_ada + 384});

  // 12. xm = modulate(ln(x1), sh_mlp, sc_mlp)
  ln_mod_kernel<<<dim3((N_NODES + 3) / 4), blk, 0, stream>>>(out, P1, xm);

  // 13. h1 = gelu(xm @ w_mlp1 + b_mlp1)  [N,512] over P1+P3
  gemm_kernel<EpiGelu><<<dim3(MB, 8), blk, 0, stream>>>(
      xm, w_mlp1, 512, h1, N_NODES, 512, 128, EpiGelu{b_mlp1});

  // 14. g_mlp into xm (xm dead after step 13)
  gemm_kernel<EpiBias><<<dim3(MB, 2), blk, 0, stream>>>(
      sgate, w_ada + 640, 768, xm, N_NODES, 128, 128, EpiBias{b_ada + 640});

  // 15. out = x1 + g_mlp * (h1 @ w_mlp2 + b_mlp2)  (in-place xres=out: safe)
  gemm_kernel<EpiResGate><<<dim3(MB, 2), blk, 0, stream>>>(
      h1, w_mlp2, 128, out, N_NODES, 128, 512, EpiResGate{b_mlp2, out, xm});
}

// Round 4
// 941.422 us; speedup vs baseline: 7.0089x; 7.0089x over previous
//
#include <hip/hip_runtime.h>
#include <math.h>

#define N_NODES 50000
#define HIDD 128
#define HEADS 8
#define HDIM 16
#define NE 800000

// ---------- dtype-robust edge-index load (clamped: can never fault) ----------
__device__ __forceinline__ int load_idx(const void* ei, int is64, long long pos) {
  long long v = is64 ? ((const long long*)ei)[pos]
                     : (long long)((const int*)ei)[pos];
  unsigned uv = (unsigned)v;
  return (uv < N_NODES) ? (int)uv : 0;
}

// int64 vs int32 detect: LE int64 < 2^31 has every odd int32 word == 0.
__global__ void detect_kernel(const unsigned* __restrict__ ei_raw, int* flag) {
  __shared__ int any_nonzero;
  if (threadIdx.x == 0) any_nonzero = 0;
  __syncthreads();
  if (threadIdx.x < 128) {
    if (ei_raw[2 * threadIdx.x + 1] != 0u) atomicOr(&any_nonzero, 1);
  }
  __syncthreads();
  if (threadIdx.x == 0) *flag = any_nonzero ? 0 : 1;  // 1 => int64
}

// ---------- ws-too-small probe: absmax ~= ws_size in MB ----------
__global__ __launch_bounds__(256) void probe_kernel(float* out, int n, float mb) {
  int i = blockIdx.x * 256 + threadIdx.x;
  if (i < n) out[i] = (i == 0) ? mb : 0.f;
}

// ---------- epilogue functors ----------
struct EpiNone {
  __device__ __forceinline__ float operator()(float a, int, int) const { return a; }
};
struct EpiBias {
  const float* b;  // pre-offset on host
  __device__ __forceinline__ float operator()(float a, int, int c) const { return a + b[c]; }
};
struct EpiGelu {
  const float* b;
  __device__ __forceinline__ float operator()(float a, int, int c) const {
    float t = a + b[c];
    float u = 0.7978845608028654f * (t + 0.044715f * t * t * t);
    return 0.5f * t * (1.f + tanhf(u));
  }
};
struct EpiResGate {  // xres[r,c] + gate[r,c] * (a + b[c]); gate is [M,128]
  const float* b;
  const float* xres;
  const float* gate;
  __device__ __forceinline__ float operator()(float a, int r, int c) const {
    return xres[(size_t)r * HIDD + c] + gate[(size_t)r * HIDD + c] * (a + b[c]);
  }
};

// ---------- tiled fp32 GEMM: C[M,N](ldc=N) = epi(A[M,K] @ B[K,*](ldb)) ----------
template <class Epi>
__global__ __launch_bounds__(256) void gemm_kernel(
    const float* __restrict__ A, const float* __restrict__ B, int ldb,
    float* __restrict__ C, int M, int N, int K, Epi epi) {
  __shared__ float As[64][68];
  __shared__ float Bs[64][64];

  const int tid = threadIdx.x;
  const int tx = tid & 15;
  const int ty = tid >> 4;
  const int row0 = blockIdx.x * 64;
  const int col0 = blockIdx.y * 64;

  float acc[4][4] = {};

  for (int k0 = 0; k0 < K; k0 += 64) {
#pragma unroll
    for (int i = 0; i < 4; i++) {
      int idx = tid + i * 256;
      int r = idx >> 4;
      int cc = (idx & 15) << 2;
      int gr = row0 + r;
      float4 v = make_float4(0.f, 0.f, 0.f, 0.f);
      if (gr < M) v = *(const float4*)(A + (size_t)gr * K + k0 + cc);
      *(float4*)&As[r][cc] = v;
    }
#pragma unroll
    for (int i = 0; i < 4; i++) {
      int idx = tid + i * 256;
      int r = idx >> 4;
      int cc = (idx & 15) << 2;
      *(float4*)&Bs[r][cc] = *(const float4*)(B + (size_t)(k0 + r) * ldb + col0 + cc);
    }
    __syncthreads();

#pragma unroll
    for (int kk = 0; kk < 64; kk++) {
      float a0 = As[ty * 4 + 0][kk];
      float a1 = As[ty * 4 + 1][kk];
      float a2 = As[ty * 4 + 2][kk];
      float a3 = As[ty * 4 + 3][kk];
      float4 b = *(float4*)&Bs[kk][tx * 4];
      acc[0][0] += a0 * b.x; acc[0][1] += a0 * b.y; acc[0][2] += a0 * b.z; acc[0][3] += a0 * b.w;
      acc[1][0] += a1 * b.x; acc[1][1] += a1 * b.y; acc[1][2] += a1 * b.z; acc[1][3] += a1 * b.w;
      acc[2][0] += a2 * b.x; acc[2][1] += a2 * b.y; acc[2][2] += a2 * b.z; acc[2][3] += a2 * b.w;
      acc[3][0] += a3 * b.x; acc[3][1] += a3 * b.y; acc[3][2] += a3 * b.z; acc[3][3] += a3 * b.w;
    }
    __syncthreads();
  }

#pragma unroll
  for (int i = 0; i < 4; i++) {
    int gr = row0 + ty * 4 + i;
    if (gr >= M) break;
    int gc = col0 + tx * 4;
    float4 o;
    o.x = epi(acc[i][0], gr, gc + 0);
    o.y = epi(acc[i][1], gr, gc + 1);
    o.z = epi(acc[i][2], gr, gc + 2);
    o.w = epi(acc[i][3], gr, gc + 3);
    *(float4*)(C + (size_t)gr * N + gc) = o;
  }
}

// ---------- silu elementwise ----------
__global__ __launch_bounds__(256) void silu_kernel(const float* __restrict__ c,
                                                   float* __restrict__ sg) {
  int i = blockIdx.x * 256 + threadIdx.x;
  if (i < N_NODES * HIDD) {
    float v = c[i];
    sg[i] = v / (1.f + __expf(-v));
  }
}

// ---------- LN + modulate: shsc rows = [sh(128)|sc(128)], stride 256 ----------
__global__ __launch_bounds__(256) void ln_mod_kernel(
    const float* __restrict__ x, const float* __restrict__ shsc,
    float* __restrict__ out) {
  int wave = threadIdx.x >> 6;
  int lane = threadIdx.x & 63;
  int row = blockIdx.x * 4 + wave;
  if (row >= N_NODES) return;
  float2 v = *(const float2*)(x + (size_t)row * HIDD + lane * 2);
  float s = v.x + v.y;
  float sq = v.x * v.x + v.y * v.y;
#pragma unroll
  for (int o = 32; o >= 1; o >>= 1) {
    s += __shfl_xor(s, o);
    sq += __shfl_xor(sq, o);
  }
  float m = s * (1.f / 128.f);
  float var = sq * (1.f / 128.f) - m * m;
  float rs = rsqrtf(var + 1e-6f);
  float2 sh = *(const float2*)(shsc + (size_t)row * 256 + lane * 2);
  float2 sc = *(const float2*)(shsc + (size_t)row * 256 + 128 + lane * 2);
  float2 o;
  o.x = (v.x - m) * rs * (1.f + sc.x) + sh.x;
  o.y = (v.y - m) * rs * (1.f + sc.y) + sh.y;
  *(float2*)(out + (size_t)row * HIDD + lane * 2) = o;
}

// ---------- CSR build ----------
__global__ __launch_bounds__(256) void zero_int_kernel(int* p, int n) {
  int i = blockIdx.x * 256 + threadIdx.x;
  if (i < n) p[i] = 0;
}

// histogram of dst into A[dst+1]
__global__ __launch_bounds__(256) void hist_kernel(const void* __restrict__ ei,
                                                   const int* __restrict__ flag,
                                                   int* __restrict__ A) {
  int e = blockIdx.x * 256 + threadIdx.x;
  if (e >= NE) return;
  int dst = load_idx(ei, *flag, (long long)NE + e);
  atomicAdd(&A[dst + 1], 1);
}

// single-block inclusive scan over A[0..n): after this A[i] = exclusive rowptr
__global__ __launch_bounds__(1024) void scan_kernel(int* __restrict__ A, int n) {
  __shared__ int buf[2][1024];
  __shared__ int carry;
  if (threadIdx.x == 0) carry = 0;
  __syncthreads();
  for (int base = 0; base < n; base += 1024) {
    int i = base + threadIdx.x;
    int val = (i < n) ? A[i] : 0;
    int pb = 0;
    buf[0][threadIdx.x] = val;
    __syncthreads();
#pragma unroll
    for (int off = 1; off < 1024; off <<= 1) {
      int t = buf[pb][threadIdx.x];
      if ((int)threadIdx.x >= off) t += buf[pb][threadIdx.x - off];
      buf[pb ^ 1][threadIdx.x] = t;
      pb ^= 1;
      __syncthreads();
    }
    int incl = buf[pb][threadIdx.x];
    if (i < n) A[i] = incl + carry;
    __syncthreads();
    if (threadIdx.x == 1023) carry += incl;
    __syncthreads();
  }
}

// scatter: pos = A[dst]++, col[pos] = src. Afterwards A[i] == orig rowptr[i+1].
__global__ __launch_bounds__(256) void scatter_kernel(const void* __restrict__ ei,
                                                      const int* __restrict__ flag,
                                                      int* __restrict__ A,
                                                      unsigned short* __restrict__ col) {
  int e = blockIdx.x * 256 + threadIdx.x;
  if (e >= NE) return;
  int is64 = *flag;
  int src = load_idx(ei, is64, e);
  int dst = load_idx(ei, is64, (long long)NE + e);
  int pos = atomicAdd(&A[dst], 1);
  col[pos] = (unsigned short)src;
}

// ---------- fused per-node attention (online softmax, zero atomics) ----------
// qk rows = [q(128)|k(128)] stride 256, h-major (head h occupies [h*16,h*16+16)).
// lane l: head h=l>>3, dims d=(l&7)*2, +1. 8-lane groups reduce dot via shfl_xor.
__global__ __launch_bounds__(256) void node_attn_kernel(
    const int* __restrict__ A, const unsigned short* __restrict__ col,
    const float* __restrict__ qk, const float* __restrict__ v,
    float* __restrict__ attn) {
  int wave = threadIdx.x >> 6;
  int lane = threadIdx.x & 63;
  int node = blockIdx.x * 4 + wave;
  if (node >= N_NODES) return;
  int start = (node == 0) ? 0 : A[node - 1];
  int end = A[node];
  float2 q = *(const float2*)(qk + (size_t)node * 256 + lane * 2);
  float m = -INFINITY, l = 0.f;
  float ax = 0.f, ay = 0.f;
  for (int p = start; p < end; p++) {
    int src = col[p];
    float2 k = *(const float2*)(qk + (size_t)src * 256 + 128 + lane * 2);
    float2 vv = *(const float2*)(v + (size_t)src * HIDD + lane * 2);
    float s = q.x * k.x + q.y * k.y;
    s += __shfl_xor(s, 1);
    s += __shfl_xor(s, 2);
    s += __shfl_xor(s, 4);
    s *= 0.25f;  // 1/sqrt(16)
    float mnew = fmaxf(m, s);
    float alpha = __expf(m - mnew);  // first iter: exp(-inf)=0
    float w = __expf(s - mnew);
    l = l * alpha + w;
    ax = ax * alpha + w * vv.x;
    ay = ay * alpha + w * vv.y;
    m = mnew;
  }
  float inv = (end > start) ? 1.f / l : 0.f;
  *(float2*)(attn + (size_t)node * HIDD + lane * 2) = make_float2(ax * inv, ay * inv);
}

extern "C" void kernel_launch(void* const* d_in, const int* in_sizes, int n_in,
                              void* d_out, int out_size, void* d_ws, size_t ws_size,
                              hipStream_t stream) {
  const float* x      = (const float*)d_in[0];
  const void*  ei     = d_in[1];
  const float* c      = (const float*)d_in[2];
  const float* w_qkv  = (const float*)d_in[3];
  const float* w_proj = (const float*)d_in[4];
  const float* b_proj = (const float*)d_in[5];
  const float* w_mlp1 = (const float*)d_in[6];
  const float* b_mlp1 = (const float*)d_in[7];
  const float* w_mlp2 = (const float*)d_in[8];
  const float* b_mlp2 = (const float*)d_in[9];
  const float* w_ada  = (const float*)d_in[10];
  const float* b_ada  = (const float*)d_in[11];
  float* out = (float*)d_out;

  // ---- pool layout (floats): xm(128) sgate(128) P1(256) P3(256) + CSR tail ----
  const size_t NM = (size_t)N_NODES;
  float* pool = (float*)d_ws;
  float* xm    = pool;                       // N*128
  float* sgate = xm + NM * 128;              // N*128
  float* P1    = sgate + NM * 128;           // N*256
  float* P3    = P1 + NM * 256;              // N*256
  int*   Arow  = (int*)(P3 + NM * 256);      // N+1 ints (rowptr, mutated by scatter)
  unsigned short* col = (unsigned short*)(Arow + (N_NODES + 1));  // E ushort
  int*   eflag = (int*)(col + NE);           // 1
  // overlays
  float* vbuf  = P1;                         // N*128 (after sh/sc dead)
  float* attn  = P1 + NM * 128;              // N*128
  float* gmsa  = P3;                         // N*128 (after qk dead)
  float* h1    = P1;                         // N*512 spans P1+P3 (adjacent)

  const size_t req_bytes =
      (NM * 768) * 4 + (N_NODES + 1) * 4 + NE * 2 + 16;
  dim3 blk(256);
  if (ws_size < req_bytes) {
    probe_kernel<<<dim3((out_size + 255) / 256), blk, 0, stream>>>(
        out, out_size, (float)(ws_size >> 20));
    return;
  }

  const int MB = (N_NODES + 63) / 64;
  const int EB = (NE + 255) / 256;
  const int NB128 = (N_NODES * 128 + 255) / 256;

  // 0. dtype detect + CSR build
  detect_kernel<<<dim3(1), blk, 0, stream>>>((const unsigned*)ei, eflag);
  zero_int_kernel<<<dim3((N_NODES + 1 + 255) / 256), blk, 0, stream>>>(Arow, N_NODES + 1);
  hist_kernel<<<dim3(EB), blk, 0, stream>>>(ei, eflag, Arow);
  scan_kernel<<<dim3(1), dim3(1024), 0, stream>>>(Arow, N_NODES + 1);
  scatter_kernel<<<dim3(EB), blk, 0, stream>>>(ei, eflag, Arow, col);

  // 1. sgate = silu(c)
  silu_kernel<<<dim3(NB128), blk, 0, stream>>>(c, sgate);

  // 2. P1 = sgate @ w_ada[:,0:256] + b  (sh_msa|sc_msa)
  gemm_kernel<EpiBias><<<dim3(MB, 4), blk, 0, stream>>>(
      sgate, w_ada, 768, P1, N_NODES, 256, 128, EpiBias{b_ada});

  // 3. xm = modulate(ln(x), sh_msa, sc_msa)
  ln_mod_kernel<<<dim3((N_NODES + 3) / 4), blk, 0, stream>>>(x, P1, xm);

  // 4. P3 = xm @ w_qkv[:,0:256]  (q|k)
  gemm_kernel<EpiNone><<<dim3(MB, 4), blk, 0, stream>>>(
      xm, w_qkv, 384, P3, N_NODES, 256, 128, EpiNone{});

  // 5. vbuf = xm @ w_qkv[:,256:384]  (sh/sc in P1 now dead)
  gemm_kernel<EpiNone><<<dim3(MB, 2), blk, 0, stream>>>(
      xm, w_qkv + 256, 384, vbuf, N_NODES, 128, 128, EpiNone{});

  // 6. fused graph attention -> attn
  node_attn_kernel<<<dim3((N_NODES + 3) / 4), blk, 0, stream>>>(Arow, col, P3, vbuf, attn);

  // 7. gmsa = sgate @ w_ada[:,256:384] + b  (qk in P3 dead)
  gemm_kernel<EpiBias><<<dim3(MB, 2), blk, 0, stream>>>(
      sgate, w_ada + 256, 768, gmsa, N_NODES, 128, 128, EpiBias{b_ada + 256});

  // 8. x1(d_out) = x + gmsa * (attn @ w_proj + b_proj)
  gemm_kernel<EpiResGate><<<dim3(MB, 2), blk, 0, stream>>>(
      attn, w_proj, 128, out, N_NODES, 128, 128, EpiResGate{b_proj, x, gmsa});

  // 9. P1 = sgate @ w_ada[:,384:640] + b  (sh_mlp|sc_mlp)
  gemm_kernel<EpiBias><<<dim3(MB, 4), blk, 0, stream>>>(
      sgate, w_ada + 384, 768, P1, N_NODES, 256, 128, EpiBias{b_ada + 384});

  // 10. xm = modulate(ln(x1), sh_mlp, sc_mlp)
  ln_mod_kernel<<<dim3((N_NODES + 3) / 4), blk, 0, stream>>>(out, P1, xm);

  // 11. h1 = gelu(xm @ w_mlp1 + b_mlp1)  [N,512] over P1+P3
  gemm_kernel<EpiGelu><<<dim3(MB, 8), blk, 0, stream>>>(
      xm, w_mlp1, 512, h1, N_NODES, 512, 128, EpiGelu{b_mlp1});

  // 12. g_mlp into xm (xm dead after 11)
  gemm_kernel<EpiBias><<<dim3(MB, 2), blk, 0, stream>>>(
      sgate, w_ada + 640, 768, xm, N_NODES, 128, 128, EpiBias{b_ada + 640});

  // 13. out = x1 + g_mlp * (h1 @ w_mlp2 + b_mlp2)  (in-place: safe)
  gemm_kernel<EpiResGate><<<dim3(MB, 2), blk, 0, stream>>>(
      h1, w_mlp2, 128, out, N_NODES, 128, 512, EpiResGate{b_mlp2, out, xm});
}

// Round 5
// 796.235 us; speedup vs baseline: 8.2869x; 1.1823x over previous
//
#include <hip/hip_runtime.h>
#include <math.h>

#define N_NODES 50000
#define HIDD 128
#define HEADS 8
#define HDIM 16
#define NE 800000

using short8 = __attribute__((ext_vector_type(8))) short;
using f32x4 = __attribute__((ext_vector_type(4))) float;

// ---------- dtype-robust edge-index load (clamped: can never fault) ----------
__device__ __forceinline__ int load_idx(const void* ei, int is64, long long pos) {
  long long v = is64 ? ((const long long*)ei)[pos]
                     : (long long)((const int*)ei)[pos];
  unsigned uv = (unsigned)v;
  return (uv < N_NODES) ? (int)uv : 0;
}

// int64 vs int32 detect: LE int64 < 2^31 has every odd int32 word == 0.
__global__ void detect_kernel(const unsigned* __restrict__ ei_raw, int* flag) {
  __shared__ int any_nonzero;
  if (threadIdx.x == 0) any_nonzero = 0;
  __syncthreads();
  if (threadIdx.x < 128) {
    if (ei_raw[2 * threadIdx.x + 1] != 0u) atomicOr(&any_nonzero, 1);
  }
  __syncthreads();
  if (threadIdx.x == 0) *flag = any_nonzero ? 0 : 1;  // 1 => int64
}

// ---------- ws-too-small probe: absmax ~= ws_size in MB ----------
__global__ __launch_bounds__(256) void probe_kernel(float* out, int n, float mb) {
  int i = blockIdx.x * 256 + threadIdx.x;
  if (i < n) out[i] = (i == 0) ? mb : 0.f;
}

// ---------- prologue / epilogue functors ----------
struct ProNone {
  __device__ __forceinline__ float operator()(float v, int, int) const { return v; }
};
struct ProSilu {
  __device__ __forceinline__ float operator()(float v, int, int) const {
    return v / (1.f + __expf(-v));
  }
};
struct EpiNone {
  __device__ __forceinline__ float operator()(float a, int, int) const { return a; }
};
struct EpiBias {
  const float* b;  // pre-offset on host
  __device__ __forceinline__ float operator()(float a, int, int c) const { return a + b[c]; }
};
struct EpiGelu {
  const float* b;
  __device__ __forceinline__ float operator()(float a, int, int c) const {
    float t = a + b[c];
    float u = 0.7978845608028654f * (t + 0.044715f * t * t * t);
    return 0.5f * t * (1.f + tanhf(u));
  }
};
struct EpiResGate {  // xres[r,c] + gate[r,c] * (a + b[c]); valid for N==128
  const float* b;
  const float* xres;
  const float* gate;
  __device__ __forceinline__ float operator()(float a, int r, int c) const {
    return xres[(size_t)r * HIDD + c] + gate[(size_t)r * HIDD + c] * (a + b[c]);
  }
};

// ---------- B pre-split: fp32 weight -> fragment-ordered bf16 hi/lo planes ----
// Element B[k][n] (n < N=1<<nshift) lands at:
//   lane = ((k>>3)&3)*16 + (n&15), j = k&7
//   dst  = (((k>>5)*(N>>4) + (n>>4))*64 + lane)*8 + j
// so a wave's b-fragment load is 64 lanes x 16 B contiguous.
__global__ __launch_bounds__(256) void convert_b_kernel(
    const float* __restrict__ B, int ldb, int nshift, int total,
    unsigned short* __restrict__ hi, unsigned short* __restrict__ lo) {
  int idx = blockIdx.x * 256 + threadIdx.x;
  if (idx >= total) return;
  int n = idx & ((1 << nshift) - 1);
  int k = idx >> nshift;
  float f = B[(size_t)k * ldb + n];
  unsigned u = __float_as_uint(f);
  unsigned short hs = (unsigned short)(u >> 16);      // truncated bf16 hi
  float hf = __uint_as_float(u & 0xFFFF0000u);
  float lf = f - hf;                                   // exact
  unsigned short ls = (unsigned short)(__float_as_uint(lf) >> 16);
  int lane = (((k >> 3) & 3) << 4) | (n & 15);
  int dst = ((((k >> 5) << (nshift - 4)) + (n >> 4)) * 64 + lane) * 8 + (k & 7);
  hi[dst] = hs;
  lo[dst] = ls;
}

// ---------- MFMA split-bf16 GEMM: C[M,N] = epi(pro(A[M,K]) @ B[K,N]) --------
// 128x128 block tile, 4 waves (2x2 of 64x64), mfma_f32_16x16x32_bf16,
// 3 MFMAs per tile (hi*hi + hi*lo + lo*hi), ~2^-17 relative error.
template <class Pro, class Epi>
__global__ __launch_bounds__(256) void mfma_gemm(
    const float* __restrict__ A,
    const unsigned short* __restrict__ Bhi, const unsigned short* __restrict__ Blo,
    float* __restrict__ C, int M, int N, int K, Pro pro, Epi epi) {
  __shared__ float As[128][68];  // +4 pad: frag reads <=2-way bank alias (free)

  const int tid = threadIdx.x;
  const int lane = tid & 63;
  const int wave = tid >> 6;
  const int wm = wave >> 1;          // wave row (0..1)
  const int wn = wave & 1;           // wave col (0..1)
  const int quad = lane >> 4;
  const int ln15 = lane & 15;
  const int row0 = blockIdx.x * 128;
  const int col0 = blockIdx.y * 128;
  const int Nt = N >> 4;
  const int ntbase = (col0 >> 4) + wn * 4;

  f32x4 acc[4][4] = {};

  for (int k0 = 0; k0 < K; k0 += 64) {
    // stage A[128][64] fp32 (prologue applied), 8 float4 per thread
#pragma unroll
    for (int i = 0; i < 8; i++) {
      int idx = tid + i * 256;
      int r = idx >> 4;
      int cc = (idx & 15) << 2;
      int gr = row0 + r;
      float4 v = make_float4(0.f, 0.f, 0.f, 0.f);
      if (gr < M) v = *(const float4*)(A + (size_t)gr * K + k0 + cc);
      v.x = pro(v.x, gr, k0 + cc + 0);
      v.y = pro(v.y, gr, k0 + cc + 1);
      v.z = pro(v.z, gr, k0 + cc + 2);
      v.w = pro(v.w, gr, k0 + cc + 3);
      *(float4*)&As[r][cc] = v;
    }
    __syncthreads();

#pragma unroll
    for (int ks = 0; ks < 2; ks++) {
      const int kb = (k0 >> 5) + ks;  // absolute 32-wide k-block
      // load 4 b-fragment pairs straight from global (L2-hot, frag-ordered)
      short8 bhi[4], blo[4];
#pragma unroll
      for (int nt = 0; nt < 4; nt++) {
        size_t off = ((size_t)(kb * Nt + ntbase + nt) * 64 + lane) * 8;
        bhi[nt] = *(const short8*)(Bhi + off);
        blo[nt] = *(const short8*)(Blo + off);
      }
#pragma unroll
      for (int mt = 0; mt < 4; mt++) {
        const int arow = wm * 64 + mt * 16 + ln15;
        const float* ap = &As[arow][ks * 32 + quad * 8];
        float4 a0 = *(const float4*)ap;
        float4 a1 = *(const float4*)(ap + 4);
        float f[8] = {a0.x, a0.y, a0.z, a0.w, a1.x, a1.y, a1.z, a1.w};
        union { unsigned u[4]; short8 v; } ch, cl;
#pragma unroll
        for (int e = 0; e < 4; e++) {
          unsigned u0 = __float_as_uint(f[2 * e]);
          unsigned u1 = __float_as_uint(f[2 * e + 1]);
          ch.u[e] = (u0 >> 16) | (u1 & 0xFFFF0000u);
          float h0 = __uint_as_float(u0 & 0xFFFF0000u);
          float h1 = __uint_as_float(u1 & 0xFFFF0000u);
          unsigned l0 = __float_as_uint(f[2 * e] - h0);
          unsigned l1 = __float_as_uint(f[2 * e + 1] - h1);
          cl.u[e] = (l0 >> 16) | (l1 & 0xFFFF0000u);
        }
        short8 ahi = ch.v, alo = cl.v;
#pragma unroll
        for (int nt = 0; nt < 4; nt++) {
          acc[mt][nt] = __builtin_amdgcn_mfma_f32_16x16x32_bf16(alo, bhi[nt], acc[mt][nt], 0, 0, 0);
          acc[mt][nt] = __builtin_amdgcn_mfma_f32_16x16x32_bf16(ahi, blo[nt], acc[mt][nt], 0, 0, 0);
          acc[mt][nt] = __builtin_amdgcn_mfma_f32_16x16x32_bf16(ahi, bhi[nt], acc[mt][nt], 0, 0, 0);
        }
      }
    }
    __syncthreads();
  }

  // epilogue: D[row = quad*4+r][col = ln15] per 16x16 tile
#pragma unroll
  for (int mt = 0; mt < 4; mt++) {
#pragma unroll
    for (int nt = 0; nt < 4; nt++) {
      f32x4 a = acc[mt][nt];
      int gc = col0 + wn * 64 + nt * 16 + ln15;
#pragma unroll
      for (int r = 0; r < 4; r++) {
        int gr = row0 + wm * 64 + mt * 16 + quad * 4 + r;
        if (gr < M) C[(size_t)gr * N + gc] = epi(a[r], gr, gc);
      }
    }
  }
}

// ---------- LN + modulate: shsc rows = [sh(128)|sc(128)], stride 256 ----------
__global__ __launch_bounds__(256) void ln_mod_kernel(
    const float* __restrict__ x, const float* __restrict__ shsc,
    float* __restrict__ out) {
  int wave = threadIdx.x >> 6;
  int lane = threadIdx.x & 63;
  int row = blockIdx.x * 4 + wave;
  if (row >= N_NODES) return;
  float2 v = *(const float2*)(x + (size_t)row * HIDD + lane * 2);
  float s = v.x + v.y;
  float sq = v.x * v.x + v.y * v.y;
#pragma unroll
  for (int o = 32; o >= 1; o >>= 1) {
    s += __shfl_xor(s, o);
    sq += __shfl_xor(sq, o);
  }
  float m = s * (1.f / 128.f);
  float var = sq * (1.f / 128.f) - m * m;
  float rs = rsqrtf(var + 1e-6f);
  float2 sh = *(const float2*)(shsc + (size_t)row * 256 + lane * 2);
  float2 sc = *(const float2*)(shsc + (size_t)row * 256 + 128 + lane * 2);
  float2 o;
  o.x = (v.x - m) * rs * (1.f + sc.x) + sh.x;
  o.y = (v.y - m) * rs * (1.f + sc.y) + sh.y;
  *(float2*)(out + (size_t)row * HIDD + lane * 2) = o;
}

// ---------- CSR build ----------
__global__ __launch_bounds__(256) void zero_int_kernel(int* p, int n) {
  int i = blockIdx.x * 256 + threadIdx.x;
  if (i < n) p[i] = 0;
}

__global__ __launch_bounds__(256) void hist_kernel(const void* __restrict__ ei,
                                                   const int* __restrict__ flag,
                                                   int* __restrict__ A) {
  int e = blockIdx.x * 256 + threadIdx.x;
  if (e >= NE) return;
  int dst = load_idx(ei, *flag, (long long)NE + e);
  atomicAdd(&A[dst + 1], 1);
}

// single-block inclusive scan; after: A[i] = exclusive rowptr
__global__ __launch_bounds__(1024) void scan_kernel(int* __restrict__ A, int n) {
  __shared__ int buf[2][1024];
  __shared__ int carry;
  if (threadIdx.x == 0) carry = 0;
  __syncthreads();
  for (int base = 0; base < n; base += 1024) {
    int i = base + threadIdx.x;
    int val = (i < n) ? A[i] : 0;
    int pb = 0;
    buf[0][threadIdx.x] = val;
    __syncthreads();
#pragma unroll
    for (int off = 1; off < 1024; off <<= 1) {
      int t = buf[pb][threadIdx.x];
      if ((int)threadIdx.x >= off) t += buf[pb][threadIdx.x - off];
      buf[pb ^ 1][threadIdx.x] = t;
      pb ^= 1;
      __syncthreads();
    }
    int incl = buf[pb][threadIdx.x];
    if (i < n) A[i] = incl + carry;
    __syncthreads();
    if (threadIdx.x == 1023) carry += incl;
    __syncthreads();
  }
}

// scatter: pos = A[dst]++, col[pos] = src. Afterwards A[i] == orig rowptr[i+1].
__global__ __launch_bounds__(256) void scatter_kernel(const void* __restrict__ ei,
                                                      const int* __restrict__ flag,
                                                      int* __restrict__ A,
                                                      unsigned short* __restrict__ col) {
  int e = blockIdx.x * 256 + threadIdx.x;
  if (e >= NE) return;
  int is64 = *flag;
  int src = load_idx(ei, is64, e);
  int dst = load_idx(ei, is64, (long long)NE + e);
  int pos = atomicAdd(&A[dst], 1);
  col[pos] = (unsigned short)src;
}

// ---------- fused per-node attention (online softmax, zero atomics) ----------
__global__ __launch_bounds__(256) void node_attn_kernel(
    const int* __restrict__ A, const unsigned short* __restrict__ col,
    const float* __restrict__ qk, const float* __restrict__ v,
    float* __restrict__ attn) {
  int wave = threadIdx.x >> 6;
  int lane = threadIdx.x & 63;
  int node = blockIdx.x * 4 + wave;
  if (node >= N_NODES) return;
  int start = (node == 0) ? 0 : A[node - 1];
  int end = A[node];
  float2 q = *(const float2*)(qk + (size_t)node * 256 + lane * 2);
  float m = -INFINITY, l = 0.f;
  float ax = 0.f, ay = 0.f;
  for (int p = start; p < end; p++) {
    int src = col[p];
    float2 k = *(const float2*)(qk + (size_t)src * 256 + 128 + lane * 2);
    float2 vv = *(const float2*)(v + (size_t)src * HIDD + lane * 2);
    float s = q.x * k.x + q.y * k.y;
    s += __shfl_xor(s, 1);
    s += __shfl_xor(s, 2);
    s += __shfl_xor(s, 4);
    s *= 0.25f;  // 1/sqrt(16)
    float mnew = fmaxf(m, s);
    float alpha = __expf(m - mnew);
    float w = __expf(s - mnew);
    l = l * alpha + w;
    ax = ax * alpha + w * vv.x;
    ay = ay * alpha + w * vv.y;
    m = mnew;
  }
  float inv = (end > start) ? 1.f / l : 0.f;
  *(float2*)(attn + (size_t)node * HIDD + lane * 2) = make_float2(ax * inv, ay * inv);
}

extern "C" void kernel_launch(void* const* d_in, const int* in_sizes, int n_in,
                              void* d_out, int out_size, void* d_ws, size_t ws_size,
                              hipStream_t stream) {
  const float* x      = (const float*)d_in[0];
  const void*  ei     = d_in[1];
  const float* c      = (const float*)d_in[2];
  const float* w_qkv  = (const float*)d_in[3];
  const float* w_proj = (const float*)d_in[4];
  const float* b_proj = (const float*)d_in[5];
  const float* w_mlp1 = (const float*)d_in[6];
  const float* b_mlp1 = (const float*)d_in[7];
  const float* w_mlp2 = (const float*)d_in[8];
  const float* b_mlp2 = (const float*)d_in[9];
  const float* w_ada  = (const float*)d_in[10];
  const float* b_ada  = (const float*)d_in[11];
  float* out = (float*)d_out;

  // ---- pool layout (floats): xm(128) P1(256) P3(256) + CSR + B planes ----
  const size_t NM = (size_t)N_NODES;
  float* pool = (float*)d_ws;
  float* xm    = pool;                       // N*128
  float* P1    = xm + NM * 128;              // N*256
  float* P3    = P1 + NM * 256;              // N*256
  int*   Arow  = (int*)(P3 + NM * 256);      // N+1 ints
  unsigned short* col = (unsigned short*)(Arow + (N_NODES + 1));  // E ushort
  int*   eflag = (int*)(col + NE);           // 1 (+pad)
  unsigned short* Bhi = (unsigned short*)(eflag + 4);   // 294912 ushort
  unsigned short* Blo = Bhi + 294912;                    // 294912 ushort
  // overlays
  float* vbuf  = P1;                         // N*128 (after sh/sc dead)
  float* attn  = P1 + NM * 128;              // N*128
  float* gmsa  = P3;                         // N*128 (after qk dead)
  float* h1    = P1;                         // N*512 spans P1+P3 (adjacent)

  // B-plane element offsets
  const size_t o_qk = 0, o_v = 32768, o_ada0 = 49152, o_gmsa = 81920,
               o_adam = 98304, o_gmlp = 131072, o_proj = 147456,
               o_mlp1 = 163840, o_mlp2 = 229376;

  const size_t req_bytes = (NM * 640) * 4 + (N_NODES + 1) * 4 + NE * 2 + 32 +
                           294912ull * 2 * 2;
  dim3 blk(256);
  if (ws_size < req_bytes) {
    probe_kernel<<<dim3((out_size + 255) / 256), blk, 0, stream>>>(
        out, out_size, (float)(ws_size >> 20));
    return;
  }

  const int MB = (N_NODES + 127) / 128;  // 391
  const int EB = (NE + 255) / 256;

  // 0. dtype detect + CSR build
  detect_kernel<<<dim3(1), blk, 0, stream>>>((const unsigned*)ei, eflag);
  zero_int_kernel<<<dim3((N_NODES + 1 + 255) / 256), blk, 0, stream>>>(Arow, N_NODES + 1);
  hist_kernel<<<dim3(EB), blk, 0, stream>>>(ei, eflag, Arow);
  scan_kernel<<<dim3(1), dim3(1024), 0, stream>>>(Arow, N_NODES + 1);
  scatter_kernel<<<dim3(EB), blk, 0, stream>>>(ei, eflag, Arow, col);

  // 0b. pre-split all weights into fragment-ordered bf16 hi/lo planes
  {
    auto cv = [&](const float* B, int ldb, int nshift, int K, size_t off) {
      int total = K << nshift;
      convert_b_kernel<<<dim3((total + 255) / 256), blk, 0, stream>>>(
          B, ldb, nshift, total, Bhi + off, Blo + off);
    };
    cv(w_qkv,        384, 8, 128, o_qk);    // q|k cols 0:256
    cv(w_qkv + 256,  384, 7, 128, o_v);     // v cols 256:384
    cv(w_ada,        768, 8, 128, o_ada0);  // sh|sc msa
    cv(w_ada + 256,  768, 7, 128, o_gmsa);  // g_msa
    cv(w_ada + 384,  768, 8, 128, o_adam);  // sh|sc mlp
    cv(w_ada + 640,  768, 7, 128, o_gmlp);  // g_mlp
    cv(w_proj,       128, 7, 128, o_proj);
    cv(w_mlp1,       512, 9, 128, o_mlp1);
    cv(w_mlp2,       128, 7, 512, o_mlp2);
  }

  // 1. P1 = silu(c) @ w_ada[:,0:256] + b  (sh_msa|sc_msa)
  mfma_gemm<ProSilu, EpiBias><<<dim3(MB, 2), blk, 0, stream>>>(
      c, Bhi + o_ada0, Blo + o_ada0, P1, N_NODES, 256, 128, ProSilu{}, EpiBias{b_ada});

  // 2. xm = modulate(ln(x), sh_msa, sc_msa)
  ln_mod_kernel<<<dim3((N_NODES + 3) / 4), blk, 0, stream>>>(x, P1, xm);

  // 3. P3 = xm @ w_qkv[:,0:256]  (q|k)
  mfma_gemm<ProNone, EpiNone><<<dim3(MB, 2), blk, 0, stream>>>(
      xm, Bhi + o_qk, Blo + o_qk, P3, N_NODES, 256, 128, ProNone{}, EpiNone{});

  // 4. vbuf = xm @ w_qkv[:,256:384]  (sh/sc in P1 dead)
  mfma_gemm<ProNone, EpiNone><<<dim3(MB, 1), blk, 0, stream>>>(
      xm, Bhi + o_v, Blo + o_v, vbuf, N_NODES, 128, 128, ProNone{}, EpiNone{});

  // 5. fused graph attention -> attn
  node_attn_kernel<<<dim3((N_NODES + 3) / 4), blk, 0, stream>>>(Arow, col, P3, vbuf, attn);

  // 6. gmsa = silu(c) @ w_ada[:,256:384] + b  (qk in P3 dead)
  mfma_gemm<ProSilu, EpiBias><<<dim3(MB, 1), blk, 0, stream>>>(
      c, Bhi + o_gmsa, Blo + o_gmsa, gmsa, N_NODES, 128, 128, ProSilu{}, EpiBias{b_ada + 256});

  // 7. x1(d_out) = x + gmsa * (attn @ w_proj + b_proj)
  mfma_gemm<ProNone, EpiResGate><<<dim3(MB, 1), blk, 0, stream>>>(
      attn, Bhi + o_proj, Blo + o_proj, out, N_NODES, 128, 128, ProNone{},
      EpiResGate{b_proj, x, gmsa});

  // 8. P1 = silu(c) @ w_ada[:,384:640] + b  (sh_mlp|sc_mlp; attn dead)
  mfma_gemm<ProSilu, EpiBias><<<dim3(MB, 2), blk, 0, stream>>>(
      c, Bhi + o_adam, Blo + o_adam, P1, N_NODES, 256, 128, ProSilu{}, EpiBias{b_ada + 384});

  // 9. xm = modulate(ln(x1), sh_mlp, sc_mlp)
  ln_mod_kernel<<<dim3((N_NODES + 3) / 4), blk, 0, stream>>>(out, P1, xm);

  // 10. h1 = gelu(xm @ w_mlp1 + b_mlp1)  [N,512] over P1+P3
  mfma_gemm<ProNone, EpiGelu><<<dim3(MB, 4), blk, 0, stream>>>(
      xm, Bhi + o_mlp1, Blo + o_mlp1, h1, N_NODES, 512, 128, ProNone{}, EpiGelu{b_mlp1});

  // 11. g_mlp into xm (xm dead after 10)
  mfma_gemm<ProSilu, EpiBias><<<dim3(MB, 1), blk, 0, stream>>>(
      c, Bhi + o_gmlp, Blo + o_gmlp, xm, N_NODES, 128, 128, ProSilu{}, EpiBias{b_ada + 640});

  // 12. out = x1 + g_mlp * (h1 @ w_mlp2 + b_mlp2)  (in-place: safe)
  mfma_gemm<ProNone, EpiResGate><<<dim3(MB, 1), blk, 0, stream>>>(
      h1, Bhi + o_mlp2, Blo + o_mlp2, out, N_NODES, 128, 512, ProNone{},
      EpiResGate{b_mlp2, out, xm});
}

// Round 6
// 725.282 us; speedup vs baseline: 9.0976x; 1.0978x over previous
//
#include <hip/hip_runtime.h>
#include <math.h>

#define N_NODES 50000
#define HIDD 128
#define HEADS 8
#define HDIM 16
#define NE 800000

using short8 = __attribute__((ext_vector_type(8))) short;
using f32x4 = __attribute__((ext_vector_type(4))) float;

// ---------- dtype-robust edge-index load (clamped: can never fault) ----------
__device__ __forceinline__ int load_idx(const void* ei, int is64, long long pos) {
  long long v = is64 ? ((const long long*)ei)[pos]
                     : (long long)((const int*)ei)[pos];
  unsigned uv = (unsigned)v;
  return (uv < N_NODES) ? (int)uv : 0;
}

// int64 vs int32 detect: LE int64 < 2^31 has every odd int32 word == 0.
__global__ void detect_kernel(const unsigned* __restrict__ ei_raw, int* flag) {
  __shared__ int any_nonzero;
  if (threadIdx.x == 0) any_nonzero = 0;
  __syncthreads();
  if (threadIdx.x < 128) {
    if (ei_raw[2 * threadIdx.x + 1] != 0u) atomicOr(&any_nonzero, 1);
  }
  __syncthreads();
  if (threadIdx.x == 0) *flag = any_nonzero ? 0 : 1;  // 1 => int64
}

// ---------- ws-too-small probe: absmax ~= ws_size in MB ----------
__global__ __launch_bounds__(256) void probe_kernel(float* out, int n, float mb) {
  int i = blockIdx.x * 256 + threadIdx.x;
  if (i < n) out[i] = (i == 0) ? mb : 0.f;
}

// ---------- prologue / epilogue functors ----------
struct ProNone {
  __device__ __forceinline__ float operator()(float v, int, int) const { return v; }
};
struct ProSilu {
  __device__ __forceinline__ float operator()(float v, int, int) const {
    return v / (1.f + __expf(-v));
  }
};
struct EpiNone {
  __device__ __forceinline__ float operator()(float a, int, int) const { return a; }
};
struct EpiBias {
  const float* b;  // pre-offset on host
  __device__ __forceinline__ float operator()(float a, int, int c) const { return a + b[c]; }
};
struct EpiGelu {
  const float* b;
  __device__ __forceinline__ float operator()(float a, int, int c) const {
    float t = a + b[c];
    float u = 0.7978845608028654f * (t + 0.044715f * t * t * t);
    return 0.5f * t * (1.f + tanhf(u));
  }
};
struct EpiResGate {  // xres[r,c] + gate[r,c] * (a + b[c]); gate/xres stride 128
  const float* b;
  const float* xres;
  const float* gate;
  __device__ __forceinline__ float operator()(float a, int r, int c) const {
    return xres[(size_t)r * HIDD + c] + gate[(size_t)r * HIDD + c] * (a + b[c]);
  }
};

// ---------- fused B pre-split: 8 segments, fragment-ordered bf16 hi/lo -------
// Element B[k][n] of segment s lands at:
//   lane = ((k>>3)&3)*16 + (n&15), j = k&7
//   dst  = dst_off + (((k>>5)*(N/16) + (n>>4))*64 + lane)*8 + j
struct CvTab {
  int end[8];      // cumulative element counts
  int src_sel[8];  // 0..4 -> which weight pointer
  int src_off[8];  // column offset into source
  int ldb[8];
  int n[8];
  int dst_off[8];
};
__global__ __launch_bounds__(256) void convert_all_kernel(
    const float* __restrict__ p0, const float* __restrict__ p1,
    const float* __restrict__ p2, const float* __restrict__ p3,
    const float* __restrict__ p4, CvTab t, int total,
    unsigned short* __restrict__ hi, unsigned short* __restrict__ lo) {
  int idx = blockIdx.x * 256 + threadIdx.x;
  if (idx >= total) return;
  int s = 0;
#pragma unroll
  for (int j = 0; j < 7; j++) s += (idx >= t.end[j]) ? 1 : 0;
  int local = idx - (s ? t.end[s - 1] : 0);
  int N = t.n[s];
  int k = (unsigned)local / (unsigned)N;
  int n = local - k * N;
  const float* B;
  int sel = t.src_sel[s];
  B = (sel == 0) ? p0 : (sel == 1) ? p1 : (sel == 2) ? p2 : (sel == 3) ? p3 : p4;
  float f = B[(size_t)k * t.ldb[s] + t.src_off[s] + n];
  unsigned u = __float_as_uint(f);
  unsigned short hs = (unsigned short)(u >> 16);  // truncated bf16 hi
  float hf = __uint_as_float(u & 0xFFFF0000u);
  unsigned short ls = (unsigned short)(__float_as_uint(f - hf) >> 16);
  int lane = (((k >> 3) & 3) << 4) | (n & 15);
  int dst = t.dst_off[s] + (((k >> 5) * (N >> 4) + (n >> 4)) * 64 + lane) * 8 + (k & 7);
  hi[dst] = hs;
  lo[dst] = ls;
}

// ---------- MFMA split-bf16 GEMM v2: LDS-staged pre-split A ------------------
// 128x128 block tile, 4 waves (2x2 of 64x64), mfma_f32_16x16x32_bf16,
// 3 MFMAs per tile (hi*hi + hi*lo + lo*hi). A split once per element at
// staging into bf16 hi/lo LDS planes (stride 72: 16B-aligned b128 reads,
// <=2-way bank alias = free); inner loop is ds_read + MFMA only.
template <class Pro, class Epi>
__global__ __launch_bounds__(256) void mfma_gemm(
    const float* __restrict__ A,
    const unsigned short* __restrict__ Bhi, const unsigned short* __restrict__ Blo,
    float* __restrict__ C, int M, int N, int K, Pro pro, Epi epi) {
  __shared__ unsigned short Ahi[128][72];
  __shared__ unsigned short Alo[128][72];

  const int tid = threadIdx.x;
  const int lane = tid & 63;
  const int wave = tid >> 6;
  const int wm = wave >> 1;
  const int wn = wave & 1;
  const int quad = lane >> 4;
  const int ln15 = lane & 15;
  const int row0 = blockIdx.x * 128;
  const int col0 = blockIdx.y * 128;
  const int Nt = N >> 4;
  const int ntbase = (col0 >> 4) + wn * 4;

  f32x4 acc[4][4] = {};

  for (int k0 = 0; k0 < K; k0 += 64) {
    // stage A[128][64]: load fp32, split to bf16 hi/lo, store LDS
#pragma unroll
    for (int i = 0; i < 8; i++) {
      int idx = tid + i * 256;
      int r = idx >> 4;
      int cc = (idx & 15) << 2;
      int gr = row0 + r;
      float4 v = make_float4(0.f, 0.f, 0.f, 0.f);
      if (gr < M) v = *(const float4*)(A + (size_t)gr * K + k0 + cc);
      v.x = pro(v.x, gr, k0 + cc + 0);
      v.y = pro(v.y, gr, k0 + cc + 1);
      v.z = pro(v.z, gr, k0 + cc + 2);
      v.w = pro(v.w, gr, k0 + cc + 3);
      unsigned u0 = __float_as_uint(v.x), u1 = __float_as_uint(v.y);
      unsigned u2 = __float_as_uint(v.z), u3 = __float_as_uint(v.w);
      unsigned hp0 = (u0 >> 16) | (u1 & 0xFFFF0000u);
      unsigned hp1 = (u2 >> 16) | (u3 & 0xFFFF0000u);
      unsigned l0 = __float_as_uint(v.x - __uint_as_float(u0 & 0xFFFF0000u));
      unsigned l1 = __float_as_uint(v.y - __uint_as_float(u1 & 0xFFFF0000u));
      unsigned l2 = __float_as_uint(v.z - __uint_as_float(u2 & 0xFFFF0000u));
      unsigned l3 = __float_as_uint(v.w - __uint_as_float(u3 & 0xFFFF0000u));
      unsigned lp0 = (l0 >> 16) | (l1 & 0xFFFF0000u);
      unsigned lp1 = (l2 >> 16) | (l3 & 0xFFFF0000u);
      *(uint2*)&Ahi[r][cc] = make_uint2(hp0, hp1);
      *(uint2*)&Alo[r][cc] = make_uint2(lp0, lp1);
    }
    __syncthreads();

#pragma unroll
    for (int ks = 0; ks < 2; ks++) {
      const int kb = (k0 >> 5) + ks;
      short8 bhi[4], blo[4];
#pragma unroll
      for (int nt = 0; nt < 4; nt++) {
        size_t off = ((size_t)(kb * Nt + ntbase + nt) * 64 + lane) * 8;
        bhi[nt] = *(const short8*)(Bhi + off);
        blo[nt] = *(const short8*)(Blo + off);
      }
#pragma unroll
      for (int mt = 0; mt < 4; mt++) {
        const int arow = wm * 64 + mt * 16 + ln15;
        short8 ahi = *(const short8*)&Ahi[arow][ks * 32 + quad * 8];
        short8 alo = *(const short8*)&Alo[arow][ks * 32 + quad * 8];
#pragma unroll
        for (int nt = 0; nt < 4; nt++) {
          acc[mt][nt] = __builtin_amdgcn_mfma_f32_16x16x32_bf16(alo, bhi[nt], acc[mt][nt], 0, 0, 0);
          acc[mt][nt] = __builtin_amdgcn_mfma_f32_16x16x32_bf16(ahi, blo[nt], acc[mt][nt], 0, 0, 0);
          acc[mt][nt] = __builtin_amdgcn_mfma_f32_16x16x32_bf16(ahi, bhi[nt], acc[mt][nt], 0, 0, 0);
        }
      }
    }
    __syncthreads();
  }

  // epilogue: D[row = quad*4+r][col = ln15] per 16x16 tile
#pragma unroll
  for (int mt = 0; mt < 4; mt++) {
#pragma unroll
    for (int nt = 0; nt < 4; nt++) {
      f32x4 a = acc[mt][nt];
      int gc = col0 + wn * 64 + nt * 16 + ln15;
#pragma unroll
      for (int r = 0; r < 4; r++) {
        int gr = row0 + wm * 64 + mt * 16 + quad * 4 + r;
        if (gr < M) C[(size_t)gr * N + gc] = epi(a[r], gr, gc);
      }
    }
  }
}

// ---------- LN + modulate: shsc rows = [sh(128)|sc(128)], stride 256 ----------
__global__ __launch_bounds__(256) void ln_mod_kernel(
    const float* __restrict__ x, const float* __restrict__ shsc,
    float* __restrict__ out) {
  int wave = threadIdx.x >> 6;
  int lane = threadIdx.x & 63;
  int row = blockIdx.x * 4 + wave;
  if (row >= N_NODES) return;
  float2 v = *(const float2*)(x + (size_t)row * HIDD + lane * 2);
  float s = v.x + v.y;
  float sq = v.x * v.x + v.y * v.y;
#pragma unroll
  for (int o = 32; o >= 1; o >>= 1) {
    s += __shfl_xor(s, o);
    sq += __shfl_xor(sq, o);
  }
  float m = s * (1.f / 128.f);
  float var = sq * (1.f / 128.f) - m * m;
  float rs = rsqrtf(var + 1e-6f);
  float2 sh = *(const float2*)(shsc + (size_t)row * 256 + lane * 2);
  float2 sc = *(const float2*)(shsc + (size_t)row * 256 + 128 + lane * 2);
  float2 o;
  o.x = (v.x - m) * rs * (1.f + sc.x) + sh.x;
  o.y = (v.y - m) * rs * (1.f + sc.y) + sh.y;
  *(float2*)(out + (size_t)row * HIDD + lane * 2) = o;
}

// ---------- CSR build ----------
__global__ __launch_bounds__(256) void zero_int_kernel(int* p, int n) {
  int i = blockIdx.x * 256 + threadIdx.x;
  if (i < n) p[i] = 0;
}

__global__ __launch_bounds__(256) void hist_kernel(const void* __restrict__ ei,
                                                   const int* __restrict__ flag,
                                                   int* __restrict__ A) {
  int e = blockIdx.x * 256 + threadIdx.x;
  if (e >= NE) return;
  int dst = load_idx(ei, *flag, (long long)NE + e);
  atomicAdd(&A[dst + 1], 1);
}

// 3-phase scan: per-block inclusive scan + block sums, wave-scan sums, add.
__global__ __launch_bounds__(1024) void scan1_kernel(int* __restrict__ A, int n,
                                                     int* __restrict__ bsum) {
  __shared__ int buf[2][1024];
  int i = blockIdx.x * 1024 + threadIdx.x;
  int val = (i < n) ? A[i] : 0;
  int pb = 0;
  buf[0][threadIdx.x] = val;
  __syncthreads();
#pragma unroll
  for (int off = 1; off < 1024; off <<= 1) {
    int t = buf[pb][threadIdx.x];
    if ((int)threadIdx.x >= off) t += buf[pb][threadIdx.x - off];
    buf[pb ^ 1][threadIdx.x] = t;
    pb ^= 1;
    __syncthreads();
  }
  int incl = buf[pb][threadIdx.x];
  if (i < n) A[i] = incl;
  if (threadIdx.x == 1023) bsum[blockIdx.x] = incl;
}
__global__ void scan2_kernel(int* __restrict__ bsum, int nb) {
  int l = threadIdx.x;  // 64 threads, nb <= 64
  int v = (l < nb) ? bsum[l] : 0;
#pragma unroll
  for (int off = 1; off < 64; off <<= 1) {
    int t = __shfl_up(v, off);
    if (l >= off) v += t;
  }
  if (l < nb) bsum[l] = v;
}
__global__ __launch_bounds__(256) void scan3_kernel(int* __restrict__ A, int n,
                                                    const int* __restrict__ bsum) {
  int i = blockIdx.x * 256 + threadIdx.x;
  int b = i >> 10;
  if (i < n && b > 0) A[i] += bsum[b - 1];
}

// scatter: pos = A[dst]++, col[pos] = src. Afterwards A[i] == orig rowptr[i+1].
__global__ __launch_bounds__(256) void scatter_kernel(const void* __restrict__ ei,
                                                      const int* __restrict__ flag,
                                                      int* __restrict__ A,
                                                      unsigned short* __restrict__ col) {
  int e = blockIdx.x * 256 + threadIdx.x;
  if (e >= NE) return;
  int is64 = *flag;
  int src = load_idx(ei, is64, e);
  int dst = load_idx(ei, is64, (long long)NE + e);
  int pos = atomicAdd(&A[dst], 1);
  col[pos] = (unsigned short)src;
}

// ---------- fused per-node attention (online softmax, 2-deep prefetch) -------
// qkv rows = [q(128)|k(128)|v(128)] stride 384, h-major.
__global__ __launch_bounds__(256) void node_attn_kernel(
    const int* __restrict__ A, const unsigned short* __restrict__ col,
    const float* __restrict__ qkv, float* __restrict__ attn) {
  int wave = threadIdx.x >> 6;
  int lane = threadIdx.x & 63;
  int node = blockIdx.x * 4 + wave;
  if (node >= N_NODES) return;
  int start = (node == 0) ? 0 : A[node - 1];
  int end = A[node];
  float2 q = *(const float2*)(qkv + (size_t)node * 384 + lane * 2);
  float m = -INFINITY, l = 0.f;
  float ax = 0.f, ay = 0.f;
  if (start < end) {
    int i0 = col[start];
    float2 kn = *(const float2*)(qkv + (size_t)i0 * 384 + 128 + lane * 2);
    float2 vn = *(const float2*)(qkv + (size_t)i0 * 384 + 256 + lane * 2);
    int i1 = (start + 1 < end) ? col[start + 1] : 0;
    for (int p = start; p < end; p++) {
      float2 kc = kn, vc = vn;
      if (p + 1 < end) {
        kn = *(const float2*)(qkv + (size_t)i1 * 384 + 128 + lane * 2);
        vn = *(const float2*)(qkv + (size_t)i1 * 384 + 256 + lane * 2);
      }
      if (p + 2 < end) i1 = col[p + 2];
      float s = q.x * kc.x + q.y * kc.y;
      s += __shfl_xor(s, 1);
      s += __shfl_xor(s, 2);
      s += __shfl_xor(s, 4);
      s *= 0.25f;  // 1/sqrt(16)
      float mnew = fmaxf(m, s);
      float alpha = __expf(m - mnew);
      float w = __expf(s - mnew);
      l = l * alpha + w;
      ax = ax * alpha + w * vc.x;
      ay = ay * alpha + w * vc.y;
      m = mnew;
    }
  }
  float inv = (end > start) ? 1.f / l : 0.f;
  *(float2*)(attn + (size_t)node * HIDD + lane * 2) = make_float2(ax * inv, ay * inv);
}

extern "C" void kernel_launch(void* const* d_in, const int* in_sizes, int n_in,
                              void* d_out, int out_size, void* d_ws, size_t ws_size,
                              hipStream_t stream) {
  const float* x      = (const float*)d_in[0];
  const void*  ei     = d_in[1];
  const float* c      = (const float*)d_in[2];
  const float* w_qkv  = (const float*)d_in[3];
  const float* w_proj = (const float*)d_in[4];
  const float* b_proj = (const float*)d_in[5];
  const float* w_mlp1 = (const float*)d_in[6];
  const float* b_mlp1 = (const float*)d_in[7];
  const float* w_mlp2 = (const float*)d_in[8];
  const float* b_mlp2 = (const float*)d_in[9];
  const float* w_ada  = (const float*)d_in[10];
  const float* b_ada  = (const float*)d_in[11];
  float* out = (float*)d_out;

  // ---- pool layout (floats): xm(128) | P1(256) | P3(384) + CSR + B planes ---
  const size_t NM = (size_t)N_NODES;
  float* pool = (float*)d_ws;
  float* xm    = pool;                       // N*128: LN out; attn overlay
  float* P1    = xm + NM * 128;              // N*256: ada shsc chunks; gmsa; h1 part
  float* P3    = P1 + NM * 256;              // N*384: qkv; h1 part; gmlp tail
  int*   Arow  = (int*)(P3 + NM * 384);      // 50048 ints (padded for alignment)
  unsigned short* col = (unsigned short*)(Arow + 50048);  // E ushort
  int*   eflag = (int*)(col + NE);           // 8 ints
  int*   bsum  = eflag + 8;                  // 64 ints
  unsigned short* Bhi = (unsigned short*)(bsum + 64);  // 294912
  unsigned short* Blo = Bhi + 294912;                  // 294912
  // overlays
  float* attn  = xm;                         // after qkv GEMM, xm dead
  float* gmsa  = P1;                         // [N,128] after ln1
  float* h1    = P1;                         // N*512 spans P1 + P3[:,0:256]
  float* gmlp  = P3 + NM * 256;              // [N,128] tail of P3

  // B-plane element offsets
  const int o_qkv = 0, o_ada0 = 49152, o_gmsa = 81920, o_adam = 98304,
            o_gmlp = 131072, o_proj = 147456, o_mlp1 = 163840, o_mlp2 = 229376;
  const int cv_total = 294912;

  const size_t req_bytes = (NM * 768) * 4 + 50048 * 4 + NE * 2 + 32 + 256 +
                           (size_t)cv_total * 2 * 2;
  dim3 blk(256);
  if (ws_size < req_bytes) {
    probe_kernel<<<dim3((out_size + 255) / 256), blk, 0, stream>>>(
        out, out_size, (float)(ws_size >> 20));
    return;
  }

  const int MB = (N_NODES + 127) / 128;  // 391
  const int EB = (NE + 255) / 256;
  const int SB = (N_NODES + 1 + 1023) / 1024;  // 49 scan blocks

  // 0. dtype detect + CSR build
  detect_kernel<<<dim3(1), blk, 0, stream>>>((const unsigned*)ei, eflag);
  zero_int_kernel<<<dim3((N_NODES + 1 + 255) / 256), blk, 0, stream>>>(Arow, N_NODES + 1);
  hist_kernel<<<dim3(EB), blk, 0, stream>>>(ei, eflag, Arow);
  scan1_kernel<<<dim3(SB), dim3(1024), 0, stream>>>(Arow, N_NODES + 1, bsum);
  scan2_kernel<<<dim3(1), dim3(64), 0, stream>>>(bsum, SB);
  scan3_kernel<<<dim3((N_NODES + 1 + 255) / 256), blk, 0, stream>>>(Arow, N_NODES + 1, bsum);
  scatter_kernel<<<dim3(EB), blk, 0, stream>>>(ei, eflag, Arow, col);

  // 0b. pre-split all weights into fragment-ordered bf16 hi/lo planes (1 launch)
  {
    CvTab t;
    // seg:            qkv     ada0    gmsa    adam    gmlp    proj    mlp1    mlp2
    int sel[8]     = { 0,      1,      1,      1,      1,      2,      3,      4 };
    int soff[8]    = { 0,      0,      256,    384,    640,    0,      0,      0 };
    int ldb[8]     = { 384,    768,    768,    768,    768,    128,    512,    128 };
    int nn[8]      = { 384,    256,    128,    256,    128,    128,    512,    128 };
    int doff[8]    = { o_qkv,  o_ada0, o_gmsa, o_adam, o_gmlp, o_proj, o_mlp1, o_mlp2 };
    int cnt[8]     = { 49152,  32768,  16384,  32768,  16384,  16384,  65536,  65536 };
    int accum = 0;
    for (int s = 0; s < 8; s++) {
      accum += cnt[s];
      t.end[s] = accum; t.src_sel[s] = sel[s]; t.src_off[s] = soff[s];
      t.ldb[s] = ldb[s]; t.n[s] = nn[s]; t.dst_off[s] = doff[s];
    }
    convert_all_kernel<<<dim3((cv_total + 255) / 256), blk, 0, stream>>>(
        w_qkv, w_ada, w_proj, w_mlp1, w_mlp2, t, cv_total, Bhi, Blo);
  }

  // 1. P1 = silu(c) @ w_ada[:,0:256] + b  (sh_msa|sc_msa)
  mfma_gemm<ProSilu, EpiBias><<<dim3(MB, 2), blk, 0, stream>>>(
      c, Bhi + o_ada0, Blo + o_ada0, P1, N_NODES, 256, 128, ProSilu{}, EpiBias{b_ada});

  // 2. xm = modulate(ln(x), sh_msa, sc_msa)
  ln_mod_kernel<<<dim3((N_NODES + 3) / 4), blk, 0, stream>>>(x, P1, xm);

  // 3. P3 = xm @ w_qkv  [N,384] = q|k|v
  mfma_gemm<ProNone, EpiNone><<<dim3(MB, 3), blk, 0, stream>>>(
      xm, Bhi + o_qkv, Blo + o_qkv, P3, N_NODES, 384, 128, ProNone{}, EpiNone{});

  // 4. fused graph attention -> attn (overlays xm; xm dead after step 3)
  node_attn_kernel<<<dim3((N_NODES + 3) / 4), blk, 0, stream>>>(Arow, col, P3, attn);

  // 5. gmsa = silu(c) @ w_ada[:,256:384] + b  (P1 shsc dead after ln1)
  mfma_gemm<ProSilu, EpiBias><<<dim3(MB, 1), blk, 0, stream>>>(
      c, Bhi + o_gmsa, Blo + o_gmsa, gmsa, N_NODES, 128, 128, ProSilu{}, EpiBias{b_ada + 256});

  // 6. x1(d_out) = x + gmsa * (attn @ w_proj + b_proj)
  mfma_gemm<ProNone, EpiResGate><<<dim3(MB, 1), blk, 0, stream>>>(
      attn, Bhi + o_proj, Blo + o_proj, out, N_NODES, 128, 128, ProNone{},
      EpiResGate{b_proj, x, gmsa});

  // 7. P1 = silu(c) @ w_ada[:,384:640] + b  (sh_mlp|sc_mlp; gmsa dead)
  mfma_gemm<ProSilu, EpiBias><<<dim3(MB, 2), blk, 0, stream>>>(
      c, Bhi + o_adam, Blo + o_adam, P1, N_NODES, 256, 128, ProSilu{}, EpiBias{b_ada + 384});

  // 8. xm = modulate(ln(x1), sh_mlp, sc_mlp)  (attn dead after step 6)
  ln_mod_kernel<<<dim3((N_NODES + 3) / 4), blk, 0, stream>>>(out, P1, xm);

  // 9. gmlp = silu(c) @ w_ada[:,640:768] + b  -> P3 tail (qkv dead after attn)
  mfma_gemm<ProSilu, EpiBias><<<dim3(MB, 1), blk, 0, stream>>>(
      c, Bhi + o_gmlp, Blo + o_gmlp, gmlp, N_NODES, 128, 128, ProSilu{}, EpiBias{b_ada + 640});

  // 10. h1 = gelu(xm @ w_mlp1 + b_mlp1)  [N,512] over P1 + P3[:,0:256]
  mfma_gemm<ProNone, EpiGelu><<<dim3(MB, 4), blk, 0, stream>>>(
      xm, Bhi + o_mlp1, Blo + o_mlp1, h1, N_NODES, 512, 128, ProNone{}, EpiGelu{b_mlp1});

  // 11. out = x1 + gmlp * (h1 @ w_mlp2 + b_mlp2)  (in-place: safe)
  mfma_gemm<ProNone, EpiResGate><<<dim3(MB, 1), blk, 0, stream>>>(
      h1, Bhi + o_mlp2, Blo + o_mlp2, out, N_NODES, 128, 512, ProNone{},
      EpiResGate{b_mlp2, out, gmlp});
}

// Round 7
// 639.048 us; speedup vs baseline: 10.3253x; 1.1349x over previous
//
#include <hip/hip_runtime.h>
#include <math.h>

#define N_NODES 50000
#define HIDD 128
#define HEADS 8
#define HDIM 16
#define NE 800000

using short8 = __attribute__((ext_vector_type(8))) short;
using f32x4 = __attribute__((ext_vector_type(4))) float;

// ---------- dtype-robust edge-index load (clamped: can never fault) ----------
__device__ __forceinline__ int load_idx(const void* ei, int is64, long long pos) {
  long long v = is64 ? ((const long long*)ei)[pos]
                     : (long long)((const int*)ei)[pos];
  unsigned uv = (unsigned)v;
  return (uv < N_NODES) ? (int)uv : 0;
}

// int64 vs int32 detect: LE int64 < 2^31 has every odd int32 word == 0.
__global__ void detect_kernel(const unsigned* __restrict__ ei_raw, int* flag) {
  __shared__ int any_nonzero;
  if (threadIdx.x == 0) any_nonzero = 0;
  __syncthreads();
  if (threadIdx.x < 128) {
    if (ei_raw[2 * threadIdx.x + 1] != 0u) atomicOr(&any_nonzero, 1);
  }
  __syncthreads();
  if (threadIdx.x == 0) *flag = any_nonzero ? 0 : 1;  // 1 => int64
}

// ---------- ws-too-small probe: absmax ~= ws_size in MB ----------
__global__ __launch_bounds__(256) void probe_kernel(float* out, int n, float mb) {
  int i = blockIdx.x * 256 + threadIdx.x;
  if (i < n) out[i] = (i == 0) ? mb : 0.f;
}

// ---------- prologue / epilogue functors ----------
struct ProNone {
  __device__ __forceinline__ float operator()(float v, int, int) const { return v; }
};
struct ProSilu {
  __device__ __forceinline__ float operator()(float v, int, int) const {
    return v / (1.f + __expf(-v));
  }
};
struct EpiNone {
  __device__ __forceinline__ float operator()(float a, int, int) const { return a; }
};
struct EpiBias {
  const float* b;  // pre-offset on host
  __device__ __forceinline__ float operator()(float a, int, int c) const { return a + b[c]; }
};
struct EpiGelu {
  const float* b;
  __device__ __forceinline__ float operator()(float a, int, int c) const {
    float t = a + b[c];
    float u = 0.7978845608028654f * (t + 0.044715f * t * t * t);
    return 0.5f * t * (1.f + tanhf(u));
  }
};
struct EpiResGate {  // xres[r,c] + gate[r,c] * (a + b[c]); gate/xres stride 128
  const float* b;
  const float* xres;
  const float* gate;
  __device__ __forceinline__ float operator()(float a, int r, int c) const {
    return xres[(size_t)r * HIDD + c] + gate[(size_t)r * HIDD + c] * (a + b[c]);
  }
};

// ---------- fused B pre-split: 8 segments, fragment-ordered bf16 hi/lo -------
// Element B[k][n] of segment s lands at:
//   lane = ((k>>3)&3)*16 + (n&15), j = k&7
//   dst  = dst_off + (((k>>5)*(N/16) + (n>>4))*64 + lane)*8 + j
struct CvTab {
  int end[8];
  int src_sel[8];
  int src_off[8];
  int ldb[8];
  int n[8];
  int dst_off[8];
};
__global__ __launch_bounds__(256) void convert_all_kernel(
    const float* __restrict__ p0, const float* __restrict__ p1,
    const float* __restrict__ p2, const float* __restrict__ p3,
    const float* __restrict__ p4, CvTab t, int total,
    unsigned short* __restrict__ hi, unsigned short* __restrict__ lo) {
  int idx = blockIdx.x * 256 + threadIdx.x;
  if (idx >= total) return;
  int s = 0;
#pragma unroll
  for (int j = 0; j < 7; j++) s += (idx >= t.end[j]) ? 1 : 0;
  int local = idx - (s ? t.end[s - 1] : 0);
  int N = t.n[s];
  int k = (unsigned)local / (unsigned)N;
  int n = local - k * N;
  const float* B;
  int sel = t.src_sel[s];
  B = (sel == 0) ? p0 : (sel == 1) ? p1 : (sel == 2) ? p2 : (sel == 3) ? p3 : p4;
  float f = B[(size_t)k * t.ldb[s] + t.src_off[s] + n];
  unsigned u = __float_as_uint(f);
  unsigned short hs = (unsigned short)(u >> 16);  // truncated bf16 hi
  float hf = __uint_as_float(u & 0xFFFF0000u);
  unsigned short ls = (unsigned short)(__float_as_uint(f - hf) >> 16);
  int lane = (((k >> 3) & 3) << 4) | (n & 15);
  int dst = t.dst_off[s] + (((k >> 5) * (N >> 4) + (n >> 4)) * 64 + lane) * 8 + (k & 7);
  hi[dst] = hs;
  lo[dst] = ls;
}

// ---------- MFMA split-bf16 GEMM v3: direct global->register A fragments -----
// No LDS, no barriers. Each wave owns a 16-row x 128-col strip.
// A-frag for 16x16x32: lane(ln15,quad) holds A[row=ln15][k=quad*8+j] — 8
// contiguous fp32 per lane; a wave's load covers 16 rows x 128 B (full lines).
// Split to bf16 hi/lo in registers; 3 MFMAs per tile (lo*hi + hi*lo + hi*hi).
template <class Pro, class Epi>
__global__ __launch_bounds__(256) void gemm_direct(
    const float* __restrict__ A,
    const unsigned short* __restrict__ Bhi, const unsigned short* __restrict__ Blo,
    float* __restrict__ C, int M, int N, int K, Pro pro, Epi epi) {
  const int tid = threadIdx.x;
  const int lane = tid & 63;
  const int wv = tid >> 6;
  const int quad = lane >> 4;
  const int ln15 = lane & 15;
  const int mrow0 = blockIdx.x * 64 + wv * 16;  // this wave's 16-row strip
  const int arow = mrow0 + ln15;                // row this lane loads for A
  const int col0 = blockIdx.y * 128;
  const int Nt = N >> 4;
  const int ntbase = col0 >> 4;
  const bool aok = (arow < M);
  const int KB = K >> 5;

  f32x4 acc[8] = {};

  for (int kb = 0; kb < KB; kb++) {
    // A fragment: 8 fp32 at row arow, cols kb*32 + quad*8
    float4 a0 = make_float4(0.f, 0.f, 0.f, 0.f), a1 = a0;
    if (aok) {
      const float* ap = A + (size_t)arow * K + kb * 32 + quad * 8;
      a0 = *(const float4*)ap;
      a1 = *(const float4*)(ap + 4);
      int cb = kb * 32 + quad * 8;
      a0.x = pro(a0.x, arow, cb + 0); a0.y = pro(a0.y, arow, cb + 1);
      a0.z = pro(a0.z, arow, cb + 2); a0.w = pro(a0.w, arow, cb + 3);
      a1.x = pro(a1.x, arow, cb + 4); a1.y = pro(a1.y, arow, cb + 5);
      a1.z = pro(a1.z, arow, cb + 6); a1.w = pro(a1.w, arow, cb + 7);
    }
    // split to bf16 hi/lo (truncation; lo compensates exactly)
    float f[8] = {a0.x, a0.y, a0.z, a0.w, a1.x, a1.y, a1.z, a1.w};
    union { unsigned u[4]; short8 v; } ch, cl;
#pragma unroll
    for (int e = 0; e < 4; e++) {
      unsigned u0 = __float_as_uint(f[2 * e]);
      unsigned u1 = __float_as_uint(f[2 * e + 1]);
      ch.u[e] = (u0 >> 16) | (u1 & 0xFFFF0000u);
      float h0 = __uint_as_float(u0 & 0xFFFF0000u);
      float h1 = __uint_as_float(u1 & 0xFFFF0000u);
      cl.u[e] = (__float_as_uint(f[2 * e] - h0) >> 16) |
                (__float_as_uint(f[2 * e + 1] - h1) & 0xFFFF0000u);
    }
    short8 ahi = ch.v, alo = cl.v;

    const unsigned short* bph = Bhi + ((size_t)(kb * Nt + ntbase) * 64 + lane) * 8;
    const unsigned short* bpl = Blo + ((size_t)(kb * Nt + ntbase) * 64 + lane) * 8;
#pragma unroll
    for (int nt = 0; nt < 8; nt++) {
      short8 bhi = *(const short8*)(bph + nt * 512);
      short8 blo = *(const short8*)(bpl + nt * 512);
      acc[nt] = __builtin_amdgcn_mfma_f32_16x16x32_bf16(alo, bhi, acc[nt], 0, 0, 0);
      acc[nt] = __builtin_amdgcn_mfma_f32_16x16x32_bf16(ahi, blo, acc[nt], 0, 0, 0);
      acc[nt] = __builtin_amdgcn_mfma_f32_16x16x32_bf16(ahi, bhi, acc[nt], 0, 0, 0);
    }
  }

  // epilogue: D[row = quad*4+r][col = ln15] per 16x16 tile
#pragma unroll
  for (int nt = 0; nt < 8; nt++) {
    f32x4 a = acc[nt];
    int gc = col0 + nt * 16 + ln15;
#pragma unroll
    for (int r = 0; r < 4; r++) {
      int gr = mrow0 + quad * 4 + r;
      if (gr < M) C[(size_t)gr * N + gc] = epi(a[r], gr, gc);
    }
  }
}

// ---------- LN + modulate: shsc rows = [sh(128)|sc(128)], stride 256 ----------
__global__ __launch_bounds__(256) void ln_mod_kernel(
    const float* __restrict__ x, const float* __restrict__ shsc,
    float* __restrict__ out) {
  int wave = threadIdx.x >> 6;
  int lane = threadIdx.x & 63;
  int row = blockIdx.x * 4 + wave;
  if (row >= N_NODES) return;
  float2 v = *(const float2*)(x + (size_t)row * HIDD + lane * 2);
  float s = v.x + v.y;
  float sq = v.x * v.x + v.y * v.y;
#pragma unroll
  for (int o = 32; o >= 1; o >>= 1) {
    s += __shfl_xor(s, o);
    sq += __shfl_xor(sq, o);
  }
  float m = s * (1.f / 128.f);
  float var = sq * (1.f / 128.f) - m * m;
  float rs = rsqrtf(var + 1e-6f);
  float2 sh = *(const float2*)(shsc + (size_t)row * 256 + lane * 2);
  float2 sc = *(const float2*)(shsc + (size_t)row * 256 + 128 + lane * 2);
  float2 o;
  o.x = (v.x - m) * rs * (1.f + sc.x) + sh.x;
  o.y = (v.y - m) * rs * (1.f + sc.y) + sh.y;
  *(float2*)(out + (size_t)row * HIDD + lane * 2) = o;
}

// ---------- CSR build ----------
__global__ __launch_bounds__(256) void zero_int_kernel(int* p, int n) {
  int i = blockIdx.x * 256 + threadIdx.x;
  if (i < n) p[i] = 0;
}

__global__ __launch_bounds__(256) void hist_kernel(const void* __restrict__ ei,
                                                   const int* __restrict__ flag,
                                                   int* __restrict__ A) {
  int e = blockIdx.x * 256 + threadIdx.x;
  if (e >= NE) return;
  int dst = load_idx(ei, *flag, (long long)NE + e);
  atomicAdd(&A[dst + 1], 1);
}

// 3-phase scan
__global__ __launch_bounds__(1024) void scan1_kernel(int* __restrict__ A, int n,
                                                     int* __restrict__ bsum) {
  __shared__ int buf[2][1024];
  int i = blockIdx.x * 1024 + threadIdx.x;
  int val = (i < n) ? A[i] : 0;
  int pb = 0;
  buf[0][threadIdx.x] = val;
  __syncthreads();
#pragma unroll
  for (int off = 1; off < 1024; off <<= 1) {
    int t = buf[pb][threadIdx.x];
    if ((int)threadIdx.x >= off) t += buf[pb][threadIdx.x - off];
    buf[pb ^ 1][threadIdx.x] = t;
    pb ^= 1;
    __syncthreads();
  }
  int incl = buf[pb][threadIdx.x];
  if (i < n) A[i] = incl;
  if (threadIdx.x == 1023) bsum[blockIdx.x] = incl;
}
__global__ void scan2_kernel(int* __restrict__ bsum, int nb) {
  int l = threadIdx.x;  // 64 threads, nb <= 64
  int v = (l < nb) ? bsum[l] : 0;
#pragma unroll
  for (int off = 1; off < 64; off <<= 1) {
    int t = __shfl_up(v, off);
    if (l >= off) v += t;
  }
  if (l < nb) bsum[l] = v;
}
__global__ __launch_bounds__(256) void scan3_kernel(int* __restrict__ A, int n,
                                                    const int* __restrict__ bsum) {
  int i = blockIdx.x * 256 + threadIdx.x;
  int b = i >> 10;
  if (i < n && b > 0) A[i] += bsum[b - 1];
}

// scatter: pos = A[dst]++, col[pos] = src. Afterwards A[i] == orig rowptr[i+1].
__global__ __launch_bounds__(256) void scatter_kernel(const void* __restrict__ ei,
                                                      const int* __restrict__ flag,
                                                      int* __restrict__ A,
                                                      unsigned short* __restrict__ col) {
  int e = blockIdx.x * 256 + threadIdx.x;
  if (e >= NE) return;
  int is64 = *flag;
  int src = load_idx(ei, is64, e);
  int dst = load_idx(ei, is64, (long long)NE + e);
  int pos = atomicAdd(&A[dst], 1);
  col[pos] = (unsigned short)src;
}

// ---------- fused per-node attention (online softmax, 2-deep prefetch) -------
// qkv rows = [q(128)|k(128)|v(128)] stride 384, h-major.
__global__ __launch_bounds__(256) void node_attn_kernel(
    const int* __restrict__ A, const unsigned short* __restrict__ col,
    const float* __restrict__ qkv, float* __restrict__ attn) {
  int wave = threadIdx.x >> 6;
  int lane = threadIdx.x & 63;
  int node = blockIdx.x * 4 + wave;
  if (node >= N_NODES) return;
  int start = (node == 0) ? 0 : A[node - 1];
  int end = A[node];
  float2 q = *(const float2*)(qkv + (size_t)node * 384 + lane * 2);
  float m = -INFINITY, l = 0.f;
  float ax = 0.f, ay = 0.f;
  if (start < end) {
    int i0 = col[start];
    float2 kn = *(const float2*)(qkv + (size_t)i0 * 384 + 128 + lane * 2);
    float2 vn = *(const float2*)(qkv + (size_t)i0 * 384 + 256 + lane * 2);
    int i1 = (start + 1 < end) ? col[start + 1] : 0;
    for (int p = start; p < end; p++) {
      float2 kc = kn, vc = vn;
      if (p + 1 < end) {
        kn = *(const float2*)(qkv + (size_t)i1 * 384 + 128 + lane * 2);
        vn = *(const float2*)(qkv + (size_t)i1 * 384 + 256 + lane * 2);
      }
      if (p + 2 < end) i1 = col[p + 2];
      float s = q.x * kc.x + q.y * kc.y;
      s += __shfl_xor(s, 1);
      s += __shfl_xor(s, 2);
      s += __shfl_xor(s, 4);
      s *= 0.25f;  // 1/sqrt(16)
      float mnew = fmaxf(m, s);
      float alpha = __expf(m - mnew);
      float w = __expf(s - mnew);
      l = l * alpha + w;
      ax = ax * alpha + w * vc.x;
      ay = ay * alpha + w * vc.y;
      m = mnew;
    }
  }
  float inv = (end > start) ? 1.f / l : 0.f;
  *(float2*)(attn + (size_t)node * HIDD + lane * 2) = make_float2(ax * inv, ay * inv);
}

extern "C" void kernel_launch(void* const* d_in, const int* in_sizes, int n_in,
                              void* d_out, int out_size, void* d_ws, size_t ws_size,
                              hipStream_t stream) {
  const float* x      = (const float*)d_in[0];
  const void*  ei     = d_in[1];
  const float* c      = (const float*)d_in[2];
  const float* w_qkv  = (const float*)d_in[3];
  const float* w_proj = (const float*)d_in[4];
  const float* b_proj = (const float*)d_in[5];
  const float* w_mlp1 = (const float*)d_in[6];
  const float* b_mlp1 = (const float*)d_in[7];
  const float* w_mlp2 = (const float*)d_in[8];
  const float* b_mlp2 = (const float*)d_in[9];
  const float* w_ada  = (const float*)d_in[10];
  const float* b_ada  = (const float*)d_in[11];
  float* out = (float*)d_out;

  // ---- pool layout (floats): xm(128) | P1(256) | P3(384) + CSR + B planes ---
  const size_t NM = (size_t)N_NODES;
  float* pool = (float*)d_ws;
  float* xm    = pool;                       // N*128: LN out; attn overlay
  float* P1    = xm + NM * 128;              // N*256: ada shsc chunks; gmsa; h1 part
  float* P3    = P1 + NM * 256;              // N*384: qkv; h1 part; gmlp tail
  int*   Arow  = (int*)(P3 + NM * 384);      // 50048 ints
  unsigned short* col = (unsigned short*)(Arow + 50048);  // E ushort
  int*   eflag = (int*)(col + NE);           // 8 ints
  int*   bsum  = eflag + 8;                  // 64 ints
  unsigned short* Bhi = (unsigned short*)(bsum + 64);  // 294912
  unsigned short* Blo = Bhi + 294912;                  // 294912
  // overlays
  float* attn  = xm;                         // after qkv GEMM, xm dead
  float* gmsa  = P1;                         // [N,128] after ln1
  float* h1    = P1;                         // N*512 spans P1 + P3[:,0:256]
  float* gmlp  = P3 + NM * 256;              // [N,128] tail of P3

  // B-plane element offsets
  const int o_qkv = 0, o_ada0 = 49152, o_gmsa = 81920, o_adam = 98304,
            o_gmlp = 131072, o_proj = 147456, o_mlp1 = 163840, o_mlp2 = 229376;
  const int cv_total = 294912;

  const size_t req_bytes = (NM * 768) * 4 + 50048 * 4 + NE * 2 + 32 + 256 +
                           (size_t)cv_total * 2 * 2;
  dim3 blk(256);
  if (ws_size < req_bytes) {
    probe_kernel<<<dim3((out_size + 255) / 256), blk, 0, stream>>>(
        out, out_size, (float)(ws_size >> 20));
    return;
  }

  const int MB = (N_NODES + 63) / 64;   // 782 row-blocks (64 rows, 4 waves)
  const int EB = (NE + 255) / 256;
  const int SB = (N_NODES + 1 + 1023) / 1024;  // 49 scan blocks

  // 0. dtype detect + CSR build
  detect_kernel<<<dim3(1), blk, 0, stream>>>((const unsigned*)ei, eflag);
  zero_int_kernel<<<dim3((N_NODES + 1 + 255) / 256), blk, 0, stream>>>(Arow, N_NODES + 1);
  hist_kernel<<<dim3(EB), blk, 0, stream>>>(ei, eflag, Arow);
  scan1_kernel<<<dim3(SB), dim3(1024), 0, stream>>>(Arow, N_NODES + 1, bsum);
  scan2_kernel<<<dim3(1), dim3(64), 0, stream>>>(bsum, SB);
  scan3_kernel<<<dim3((N_NODES + 1 + 255) / 256), blk, 0, stream>>>(Arow, N_NODES + 1, bsum);
  scatter_kernel<<<dim3(EB), blk, 0, stream>>>(ei, eflag, Arow, col);

  // 0b. pre-split all weights into fragment-ordered bf16 hi/lo planes (1 launch)
  {
    CvTab t;
    // seg:            qkv     ada0    gmsa    adam    gmlp    proj    mlp1    mlp2
    int sel[8]     = { 0,      1,      1,      1,      1,      2,      3,      4 };
    int soff[8]    = { 0,      0,      256,    384,    640,    0,      0,      0 };
    int ldb[8]     = { 384,    768,    768,    768,    768,    128,    512,    128 };
    int nn[8]      = { 384,    256,    128,    256,    128,    128,    512,    128 };
    int doff[8]    = { o_qkv,  o_ada0, o_gmsa, o_adam, o_gmlp, o_proj, o_mlp1, o_mlp2 };
    int cnt[8]     = { 49152,  32768,  16384,  32768,  16384,  16384,  65536,  65536 };
    int accum = 0;
    for (int s = 0; s < 8; s++) {
      accum += cnt[s];
      t.end[s] = accum; t.src_sel[s] = sel[s]; t.src_off[s] = soff[s];
      t.ldb[s] = ldb[s]; t.n[s] = nn[s]; t.dst_off[s] = doff[s];
    }
    convert_all_kernel<<<dim3((cv_total + 255) / 256), blk, 0, stream>>>(
        w_qkv, w_ada, w_proj, w_mlp1, w_mlp2, t, cv_total, Bhi, Blo);
  }

  // 1. P1 = silu(c) @ w_ada[:,0:256] + b  (sh_msa|sc_msa)
  gemm_direct<ProSilu, EpiBias><<<dim3(MB, 2), blk, 0, stream>>>(
      c, Bhi + o_ada0, Blo + o_ada0, P1, N_NODES, 256, 128, ProSilu{}, EpiBias{b_ada});

  // 2. xm = modulate(ln(x), sh_msa, sc_msa)
  ln_mod_kernel<<<dim3((N_NODES + 3) / 4), blk, 0, stream>>>(x, P1, xm);

  // 3. P3 = xm @ w_qkv  [N,384] = q|k|v
  gemm_direct<ProNone, EpiNone><<<dim3(MB, 3), blk, 0, stream>>>(
      xm, Bhi + o_qkv, Blo + o_qkv, P3, N_NODES, 384, 128, ProNone{}, EpiNone{});

  // 4. fused graph attention -> attn (overlays xm; xm dead after step 3)
  node_attn_kernel<<<dim3((N_NODES + 3) / 4), blk, 0, stream>>>(Arow, col, P3, attn);

  // 5. gmsa = silu(c) @ w_ada[:,256:384] + b  (P1 shsc dead after ln1)
  gemm_direct<ProSilu, EpiBias><<<dim3(MB, 1), blk, 0, stream>>>(
      c, Bhi + o_gmsa, Blo + o_gmsa, gmsa, N_NODES, 128, 128, ProSilu{}, EpiBias{b_ada + 256});

  // 6. x1(d_out) = x + gmsa * (attn @ w_proj + b_proj)
  gemm_direct<ProNone, EpiResGate><<<dim3(MB, 1), blk, 0, stream>>>(
      attn, Bhi + o_proj, Blo + o_proj, out, N_NODES, 128, 128, ProNone{},
      EpiResGate{b_proj, x, gmsa});

  // 7. P1 = silu(c) @ w_ada[:,384:640] + b  (sh_mlp|sc_mlp; gmsa dead)
  gemm_direct<ProSilu, EpiBias><<<dim3(MB, 2), blk, 0, stream>>>(
      c, Bhi + o_adam, Blo + o_adam, P1, N_NODES, 256, 128, ProSilu{}, EpiBias{b_ada + 384});

  // 8. xm = modulate(ln(x1), sh_mlp, sc_mlp)  (attn dead after step 6)
  ln_mod_kernel<<<dim3((N_NODES + 3) / 4), blk, 0, stream>>>(out, P1, xm);

  // 9. gmlp = silu(c) @ w_ada[:,640:768] + b  -> P3 tail (qkv dead after attn)
  gemm_direct<ProSilu, EpiBias><<<dim3(MB, 1), blk, 0, stream>>>(
      c, Bhi + o_gmlp, Blo + o_gmlp, gmlp, N_NODES, 128, 128, ProSilu{}, EpiBias{b_ada + 640});

  // 10. h1 = gelu(xm @ w_mlp1 + b_mlp1)  [N,512] over P1 + P3[:,0:256]
  gemm_direct<ProNone, EpiGelu><<<dim3(MB, 4), blk, 0, stream>>>(
      xm, Bhi + o_mlp1, Blo + o_mlp1, h1, N_NODES, 512, 128, ProNone{}, EpiGelu{b_mlp1});

  // 11. out = x1 + gmlp * (h1 @ w_mlp2 + b_mlp2)  (in-place: safe)
  gemm_direct<ProNone, EpiResGate><<<dim3(MB, 1), blk, 0, stream>>>(
      h1, Bhi + o_mlp2, Blo + o_mlp2, out, N_NODES, 128, 512, ProNone{},
      EpiResGate{b_mlp2, out, gmlp});
}